// Round 29
// baseline (423.505 us; speedup 1.0000x reference)
//
#include <hip/hip_runtime.h>
#include <hip/hip_bf16.h>
#include <math.h>

#define BN_ 32
#define CIN 512
#define KN 1024
#define CMID 128
#define COUT 64
#define NCLS 5
#define NUM_TOP 205
#define NUM_KEPT 409
#define NUM_DROP 410
#define ADJ_KK 204
#define EPSF 1e-8f
#define INV_DS (1.0f / 0.599609375f)

typedef __bf16 bf16x8 __attribute__((ext_vector_type(8)));
typedef float f32x4 __attribute__((ext_vector_type(4)));

__device__ inline ushort f2bf(float x) {
  union { __hip_bfloat16 b; ushort u; } c;
  c.b = __float2bfloat16(x);
  return c.u;
}

// async global->LDS, 16B per lane (dest = wave-uniform base + lane*16)
__device__ inline void gll16(const ushort* g, ushort* l) {
  __builtin_amdgcn_global_load_lds(
      (const __attribute__((address_space(1))) unsigned int*)g,
      (__attribute__((address_space(3))) unsigned int*)l, 16, 0, 0);
}

// ------- fused top-mask rank + adjP row-sum, 4-way j-split ---------------
__global__ __launch_bounds__(256) void maskpsum_kernel(const float* __restrict__ imp,
                                                       float* __restrict__ topM,
                                                       float* __restrict__ invSumP) {
  int b = blockIdx.y;
  int t = threadIdx.x;
  int io = t >> 2;
  int part = t & 3;
  int i = blockIdx.x * 64 + io;
  __shared__ float im[KN];
  for (int j = t; j < KN; j += 256) im[j] = imp[(size_t)b * KN + j];
  __syncthreads();
  float vi = im[i];
  int j0 = part * 256;
  int rank = 0;
  float s = 0.0f;
#pragma unroll 4
  for (int jj = 0; jj < 256; ++jj) {
    int j = j0 + jj;
    float a = im[j];
    rank += (a > vi || (a == vi && j < i)) ? 1 : 0;
    float d = vi - a;
    s += __expf(-d * d * 0.125f);
  }
  rank += __shfl_xor(rank, 1);
  rank += __shfl_xor(rank, 2);
  s += __shfl_xor(s, 1);
  s += __shfl_xor(s, 2);
  if (part == 0) {
    topM[(size_t)b * KN + i] = (rank < NUM_TOP) ? 1.0f : 0.0f;
    invSumP[(size_t)b * KN + i] = 1.0f / (s + 1.0f + EPSF);
  }
}

// ------- masks stage 2: kept/drop ranks, 4-way j-split (integer-exact) ---
__global__ __launch_bounds__(256) void masks2_kernel(const float* __restrict__ rnd,
                                                     const float* __restrict__ topM,
                                                     float* __restrict__ mTK,
                                                     float* __restrict__ mTD) {
  int b = blockIdx.y;
  int t = threadIdx.x;
  int io = t >> 2;
  int part = t & 3;
  int i = blockIdx.x * 64 + io;
  __shared__ float r1s[KN];
  __shared__ float r2s[KN];
  for (int j = t; j < KN; j += 256) {
    float tv = topM[(size_t)b * KN + j];
    float rv = rnd[(size_t)b * KN + j];
    r1s[j] = (tv > 0.5f) ? -10.0f : rv;
    r2s[j] = (tv > 0.5f) ? 10.0f : rv;
  }
  __syncthreads();
  float v1 = r1s[i];
  float v2 = r2s[i];
  int j0 = part * 256;
  int c1 = 0, c2 = 0;
#pragma unroll 4
  for (int jj = 0; jj < 256; ++jj) {
    int j = j0 + jj;
    float a = r1s[j];
    float bb2 = r2s[j];
    c1 += (a > v1 || (a == v1 && j < i)) ? 1 : 0;
    c2 += (bb2 < v2 || (bb2 == v2 && j < i)) ? 1 : 0;
  }
  c1 += __shfl_xor(c1, 1);
  c1 += __shfl_xor(c1, 2);
  c2 += __shfl_xor(c2, 1);
  c2 += __shfl_xor(c2, 2);
  if (part == 0) {
    int top = topM[(size_t)b * KN + i] > 0.5f;
    mTK[(size_t)b * KN + i] = (top || c1 < NUM_KEPT) ? 1.0f : 0.0f;
    mTD[(size_t)b * KN + i] = (top || c2 < NUM_DROP) ? 1.0f : 0.0f;
  }
}

// ---------------- per-column L2 norm: inv and nrm ------------------------
template <int C>
__global__ void colnorm_kernel(const float* __restrict__ f, float* __restrict__ inv,
                               float* __restrict__ nrm) {
  int idx = blockIdx.x * 256 + threadIdx.x;
  int b = idx >> 10;
  int k = idx & (KN - 1);
  const float* fb = f + (size_t)b * C * KN + k;
  float ss = 0.0f;
  for (int c = 0; c < C; ++c) {
    float v = fb[(size_t)c * KN];
    ss += v * v;
  }
  float n = sqrtf(ss) + EPSF;
  inv[idx] = 1.0f / n;
  nrm[idx] = n;
}

// ------- WT[o][c] = bf16(W[c][o]) for W[R][CC] row-major -----------------
template <int R, int CC>
__global__ __launch_bounds__(256) void wtrans_kernel(const float* __restrict__ W,
                                                     ushort* __restrict__ WT) {
  int idx = blockIdx.x * 256 + threadIdx.x;  // CC*R total
  int o = idx / R;
  int c = idx - o * R;
  WT[(size_t)o * R + c] = f2bf(W[(size_t)c * CC + o]);
}

// ------- transpose+normalize+bf16 into GROUP-LOCAL buffer ---------------
template <int C>
__global__ void xpose_kernel(const float* __restrict__ f, const float* __restrict__ inv,
                             __hip_bfloat16* __restrict__ oT, int bstart) {
  int brel = blockIdx.z;
  int b = bstart + brel;
  int k0 = blockIdx.x * 64;
  int c0 = blockIdx.y * 64;
  __shared__ float t[64][65];
  const float* fb = f + (size_t)b * C * KN;
  int tx = threadIdx.x & 63;
  int ty = threadIdx.x >> 6;
  for (int r = 0; r < 64; r += 4) t[r + ty][tx] = fb[(size_t)(c0 + r + ty) * KN + k0 + tx];
  __syncthreads();
  __hip_bfloat16* ob = oT + (size_t)brel * KN * C;
  for (int r = 0; r < 64; r += 4) {
    int k = r + ty;
    float s = inv[(size_t)b * KN + k0 + k];
    ob[(size_t)(k0 + k) * C + c0 + tx] = __float2bfloat16(t[tx][k] * s);
  }
}

// ---------------- MFMA sim: sim = XnT * XnT^T, bf16 out ------------------
// SYMMETRY: only ti<=tj tiles computed (36 of 64). Off-diagonal tiles also
// write the mirror tile via block-level LDS transpose with FULL 256B-row
// stores (partial-line mirror writes were R23's write-allocate trap).
// Mirror values bit-identical: MFMA dot is element-commutative, same order.
template <int C>
__global__ __launch_bounds__(256) void simf_kernel(const ushort* __restrict__ xT,
                                                   float* __restrict__ sim, int nb) {
  (void)nb;
  int f = blockIdx.x;
  int brel = f / 36;
  int rem = f - brel * 36;
  int ti = 0;
  while (rem >= 8 - ti) {
    rem -= 8 - ti;
    ++ti;
  }
  int tj = ti + rem;
  int t = threadIdx.x;
  int lane = t & 63;
  int wid = t >> 6;
  int iB = ti * 128;
  int jB = tj * 128;
  const ushort* X = xT + (size_t)brel * KN * C;

  __shared__ ushort smem[16384];  // As[2][4096] | Bs[2][4096]; ep aliases base
  ushort* AsB = smem;
  ushort* BsB = smem + 8192;

  int srow = t >> 2;
  int scol = (((t & 3) ^ ((t >> 3) & 3))) * 8;  // pre-swizzled global seg
  int ldst = t * 8;                             // linear LDS dest

  auto stage = [&](int bufi, int c0) {
    gll16(X + (size_t)(iB + srow) * C + c0 + scol, &AsB[bufi * 4096 + ldst]);
    gll16(X + (size_t)(iB + 64 + srow) * C + c0 + scol, &AsB[bufi * 4096 + 2048 + ldst]);
    gll16(X + (size_t)(jB + srow) * C + c0 + scol, &BsB[bufi * 4096 + ldst]);
    gll16(X + (size_t)(jB + 64 + srow) * C + c0 + scol, &BsB[bufi * 4096 + 2048 + ldst]);
  };

  int i0loc = (wid >> 1) * 64;
  int j0loc = (wid & 1) * 64;
  int r = lane & 15;
  int sseg = lane >> 4;

  f32x4 acc[4][4] = {};
  stage(0, 0);
  __syncthreads();
  constexpr int NT = C / 32;
  int cur = 0;
#pragma unroll 2
  for (int ks = 0; ks < NT; ++ks) {
    if (ks + 1 < NT) stage(cur ^ 1, (ks + 1) * 32);
    bf16x8 a[4], bb[4];
#pragma unroll
    for (int m = 0; m < 4; ++m) {
      int row = i0loc + m * 16 + r;
      int off = row * 32 + ((sseg ^ ((row >> 1) & 3)) << 3);
      a[m] = *reinterpret_cast<const bf16x8*>(&AsB[cur * 4096 + off]);
    }
#pragma unroll
    for (int n = 0; n < 4; ++n) {
      int row = j0loc + n * 16 + r;
      int off = row * 32 + ((sseg ^ ((row >> 1) & 3)) << 3);
      bb[n] = *reinterpret_cast<const bf16x8*>(&BsB[cur * 4096 + off]);
    }
#pragma unroll
    for (int m = 0; m < 4; ++m)
#pragma unroll
      for (int n = 0; n < 4; ++n)
        acc[m][n] = __builtin_amdgcn_mfma_f32_16x16x32_bf16(a[m], bb[n], acc[m][n], 0, 0, 0);
    __syncthreads();
    cur ^= 1;
  }

  // primary epilogue: per-wave LDS transpose aliased onto dead staging bufs
  float(*buf)[65] = (float(*)[65])((float*)smem + (size_t)wid * 16 * 65);
  int orow = (lane >> 4) * 4;
  int ocol = lane & 15;
  int i0 = iB + i0loc;
  int j0 = jB + j0loc;
  ushort* simb = (ushort*)sim + (size_t)brel * KN * 2048;
#pragma unroll
  for (int m = 0; m < 4; ++m) {
#pragma unroll
    for (int n = 0; n < 4; ++n)
#pragma unroll
      for (int rr = 0; rr < 4; ++rr) buf[orow + rr][n * 16 + ocol] = acc[m][n][rr];
#pragma unroll
    for (int rr = 0; rr < 4; ++rr) {
      int row = rr * 4 + (lane >> 4);
      float4 v4 = *(const float4*)&buf[row][(lane & 15) * 4];
      ushort4 r4;
      r4.x = f2bf(v4.x);
      r4.y = f2bf(v4.y);
      r4.z = f2bf(v4.z);
      r4.w = f2bf(v4.w);
      *(ushort4*)(simb + (size_t)(i0 + m * 16 + row) * 2048 + j0 + (lane & 15) * 4) = r4;
    }
  }

  // mirror pass: whole-block 128x128 bf16 transpose in smem, full-row stores
  if (iB != jB) {
    __syncthreads();  // all waves done with primary epilogue bufs
    ushort* Tm = smem;  // [128][128] ushort = 32KB, XOR-swz on 8B units
#pragma unroll
    for (int m = 0; m < 4; ++m)
#pragma unroll
      for (int n = 0; n < 4; ++n) {
        int cu = ((i0loc + m * 16) >> 2) + (lane >> 4);  // data col unit (0..31)
        int row = j0loc + n * 16 + (lane & 15);
        int u = cu ^ (row & 15);
        ushort4 val;
        val.x = f2bf(acc[m][n][0]);
        val.y = f2bf(acc[m][n][1]);
        val.z = f2bf(acc[m][n][2]);
        val.w = f2bf(acc[m][n][3]);
        *(ushort4*)&Tm[row * 128 + u * 4] = val;
      }
    __syncthreads();
    int row = t >> 1;
    int half = t & 1;
    ushort* dstrow = simb + (size_t)(jB + row) * 2048 + iB;
#pragma unroll
    for (int k = 0; k < 16; ++k) {
      int cu = half * 16 + k;
      int u = cu ^ (row & 15);
      *(ushort4*)(dstrow + cu * 4) = *(const ushort4*)&Tm[row * 128 + u * 4];
    }
  }
}

// ------- fused per-wave threshold select + finalize (bf16 sim) -----------
__global__ __launch_bounds__(256) void thrfin_kernel(float* __restrict__ A,
                                                     const float* __restrict__ imp,
                                                     const float* __restrict__ invSumP,
                                                     int bstart) {
  int brel = blockIdx.y;
  int b = bstart + brel;
  int wid = threadIdx.x >> 6;
  int lane = threadIdx.x & 63;
  int i = blockIdx.x * 4 + wid;
  ushort* row = (ushort*)A + ((size_t)brel * KN + i) * 2048;
  __shared__ float im[KN];
  ((float4*)im)[threadIdx.x] = ((const float4*)(imp + (size_t)b * KN))[threadIdx.x];
  __syncthreads();

  ushort4 v[4];
  unsigned key[16];
#pragma unroll
  for (int q = 0; q < 4; ++q) v[q] = ((const ushort4*)row)[lane + 64 * q];
#pragma unroll
  for (int q = 0; q < 4; ++q) {
    const ushort* pv = (const ushort*)&v[q];
#pragma unroll
    for (int e = 0; e < 4; ++e) {
      ushort u = pv[e];
      key[q * 4 + e] = (u & 0x8000u) ? (unsigned)(ushort)~u : (unsigned)(u | 0x8000u);
    }
  }
  unsigned tk = 0u;
#pragma unroll 1
  for (int bit = 15; bit >= 0; --bit) {
    unsigned cand = tk | (1u << bit);
    int c = 0;
#pragma unroll
    for (int e = 0; e < 8; ++e)
      c += (int)__popcll(__ballot(key[e] >= cand));
    int cl = 0;
#pragma unroll
    for (int e = 8; e < 16; ++e) cl += (key[e] >= cand) ? 1 : 0;
#pragma unroll
    for (int off = 32; off > 0; off >>= 1) cl += __shfl_xor(cl, off);
    c += cl;
    if (c >= ADJ_KK) tk = cand;
  }
  float m[16];
  float s = 0.0f;
#pragma unroll
  for (int q = 0; q < 4; ++q) {
    const ushort* pv = (const ushort*)&v[q];
#pragma unroll
    for (int e = 0; e < 4; ++e) {
      float val = __uint_as_float(((unsigned)pv[e]) << 16);
      float mv = (key[q * 4 + e] >= tk) ? val : 0.0f;
      m[q * 4 + e] = mv;
      s += mv;
    }
  }
#pragma unroll
  for (int off = 32; off > 0; off >>= 1) s += __shfl_xor(s, off);
  float invF = 1.0f / (s + 1.0f + EPSF);
  float vi = im[i];
  float invP = invSumP[(size_t)b * KN + i];
#pragma unroll
  for (int q = 0; q < 4; ++q) {
    float4 iv = ((const float4*)im)[lane + 64 * q];
    const float* ip = (const float*)&iv;
    ushort4 r;
    ushort* rp = (ushort*)&r;
    int colb = 4 * lane + 256 * q;
#pragma unroll
    for (int e = 0; e < 4; ++e) {
      float diag = (colb + e == i) ? 1.0f : 0.0f;
      float d = vi - ip[e];
      rp[e] = f2bf((m[q * 4 + e] + diag) * invF + (__expf(-d * d * 0.125f) + diag) * invP);
    }
    ((ushort4*)row)[lane + 64 * q] = r;
  }
}

// ------- bf16 transpose INTO sim rows' back halves -----------------------
__global__ __launch_bounds__(256) void at_kernel(float* __restrict__ Asim) {
  int brel = blockIdx.z;
  int k0 = blockIdx.x * 64;
  int j0 = blockIdx.y * 64;
  __shared__ ushort t[64][68];
  ushort* Ab = (ushort*)(Asim + (size_t)brel * KN * KN);
  int g = threadIdx.x & 15;
  int r = threadIdx.x >> 4;
#pragma unroll
  for (int p = 0; p < 4; ++p) {
    int row = p * 16 + r;
    *(ushort4*)&t[row][g * 4] =
        *(const ushort4*)&Ab[(size_t)(k0 + row) * 2048 + j0 + g * 4];
  }
  __syncthreads();
#pragma unroll
  for (int p = 0; p < 4; ++p) {
    int j = p * 16 + r;
    ushort4 v;
    v.x = t[g * 4 + 0][j];
    v.y = t[g * 4 + 1][j];
    v.z = t[g * 4 + 2][j];
    v.w = t[g * 4 + 3][j];
    *(ushort4*)&Ab[(size_t)(j0 + j) * 2048 + 1024 + k0 + g * 4] = v;
  }
}

// ---------------- MFMA linear: hg[brel,o,k] = fac(k)*sum_c WT[o,c]*fT[k,c]
// fac = nrm[k] (layer 1) or mTK[k]*INV_DS*nrm[k] (layer 2).
// Epilogue aliased onto dead staging buffers.
template <int C, bool MASK>
__global__ __launch_bounds__(256) void linf_kernel(const ushort* __restrict__ xg,
                                                   const ushort* __restrict__ WT,
                                                   const float* __restrict__ nrm,
                                                   const float* __restrict__ mTK,
                                                   ushort* __restrict__ hg, int M,
                                                   int bstart) {
  int brel = blockIdx.z;
  int b = bstart + brel;
  int t = threadIdx.x;
  int lane = t & 63;
  int wid = t >> 6;
  int iB = blockIdx.y * 64;
  int jB = blockIdx.x * 128;
  const ushort* xb = xg + (size_t)brel * KN * C;

  __shared__ ushort smem[12288];  // Hs[2][2048] | Bs[2][4096]; ep aliases base
  ushort* HsB = smem;
  ushort* BsB = smem + 4096;

  int srow = t >> 2;
  int scol = (t & 3) * 8;
  int ldst = t * 8;

  auto stage = [&](int bufi, int c0) {
    gll16(WT + (size_t)(iB + srow) * C + c0 + scol, &HsB[bufi * 2048 + ldst]);
    gll16(xb + (size_t)(jB + srow) * C + c0 + scol, &BsB[bufi * 4096 + ldst]);
    gll16(xb + (size_t)(jB + 64 + srow) * C + c0 + scol, &BsB[bufi * 4096 + 2048 + ldst]);
  };

  int i0loc = (wid >> 1) * 32;
  int j0loc = (wid & 1) * 64;
  int r = lane & 15;
  int s = (lane >> 4) * 8;

  f32x4 acc[2][4] = {};
  stage(0, 0);
  __syncthreads();
  int cur = 0;
#pragma unroll 2
  for (int ks = 0; ks < C / 32; ++ks) {
    if (ks + 1 < C / 32) stage(cur ^ 1, (ks + 1) * 32);
    bf16x8 a[2], bb[4];
#pragma unroll
    for (int m = 0; m < 2; ++m)
      a[m] = *reinterpret_cast<const bf16x8*>(&HsB[cur * 2048 + (i0loc + m * 16 + r) * 32 + s]);
#pragma unroll
    for (int n = 0; n < 4; ++n)
      bb[n] = *reinterpret_cast<const bf16x8*>(&BsB[cur * 4096 + (j0loc + n * 16 + r) * 32 + s]);
#pragma unroll
    for (int m = 0; m < 2; ++m)
#pragma unroll
      for (int n = 0; n < 4; ++n)
        acc[m][n] = __builtin_amdgcn_mfma_f32_16x16x32_bf16(a[m], bb[n], acc[m][n], 0, 0, 0);
    __syncthreads();
    cur ^= 1;
  }

  float(*buf)[65] = (float(*)[65])((float*)smem + (size_t)wid * 16 * 65);
  int orow = (lane >> 4) * 4;
  int ocol = lane & 15;
  int i0 = iB + i0loc;
  int j0 = jB + j0loc;
#pragma unroll
  for (int m = 0; m < 2; ++m) {
#pragma unroll
    for (int n = 0; n < 4; ++n)
#pragma unroll
      for (int rr = 0; rr < 4; ++rr) buf[orow + rr][n * 16 + ocol] = acc[m][n][rr];
#pragma unroll
    for (int rr = 0; rr < 4; ++rr) {
      int row = rr * 4 + (lane >> 4);
      int kk = j0 + (lane & 15) * 4;
      float4 v4 = *(const float4*)&buf[row][(lane & 15) * 4];
      float4 nv = *(const float4*)(nrm + (size_t)b * KN + kk);
      float f0 = nv.x, f1 = nv.y, f2 = nv.z, f3 = nv.w;
      if (MASK) {
        float4 mv = *(const float4*)(mTK + (size_t)b * KN + kk);
        f0 *= mv.x * INV_DS;
        f1 *= mv.y * INV_DS;
        f2 *= mv.z * INV_DS;
        f3 *= mv.w * INV_DS;
      }
      ushort4 r4;
      r4.x = f2bf(v4.x * f0);
      r4.y = f2bf(v4.y * f1);
      r4.z = f2bf(v4.z * f2);
      r4.w = f2bf(v4.w * f3);
      *(ushort4*)(hg + ((size_t)brel * M + i0 + m * 16 + row) * KN + kk) = r4;
    }
  }
}

// ---------------- MFMA s = relu(h @ A), At read from sim back halves -----
// Epilogue aliased onto dead staging buffers (24KB LDS total).
template <int M, bool LOCAL>
__global__ __launch_bounds__(256) void sgemmf_kernel(const ushort* __restrict__ hB,
                                                     const float* __restrict__ Asim,
                                                     float* __restrict__ outp, int bstart) {
  int brel = blockIdx.z;
  int b = bstart + brel;
  int t = threadIdx.x;
  int lane = t & 63;
  int wid = t >> 6;
  int iB = blockIdx.y * 64;
  int jB = blockIdx.x * 128;
  const ushort* hb = hB + (size_t)(LOCAL ? brel : b) * M * KN;
  const ushort* Ab = (const ushort*)(Asim + (size_t)brel * KN * KN);

  __shared__ ushort smem[12288];  // Hs[2][2048] | Bs[2][4096]; ep aliases base
  ushort* HsB = smem;
  ushort* BsB = smem + 4096;

  int srow = t >> 2;
  int scol = (t & 3) * 8;
  int ldst = t * 8;

  auto stage = [&](int bufi, int k0) {
    gll16(hb + (size_t)(iB + srow) * KN + k0 + scol, &HsB[bufi * 2048 + ldst]);
    gll16(Ab + (size_t)(jB + srow) * 2048 + 1024 + k0 + scol, &BsB[bufi * 4096 + ldst]);
    gll16(Ab + (size_t)(jB + 64 + srow) * 2048 + 1024 + k0 + scol,
          &BsB[bufi * 4096 + 2048 + ldst]);
  };

  int i0loc = (wid >> 1) * 32;
  int j0loc = (wid & 1) * 64;
  int r = lane & 15;
  int s = (lane >> 4) * 8;

  f32x4 acc[2][4] = {};
  stage(0, 0);
  __syncthreads();
  int cur = 0;
#pragma unroll 2
  for (int ks = 0; ks < KN / 32; ++ks) {
    if (ks + 1 < KN / 32) stage(cur ^ 1, (ks + 1) * 32);
    bf16x8 a[2], bb[4];
#pragma unroll
    for (int m = 0; m < 2; ++m)
      a[m] = *reinterpret_cast<const bf16x8*>(&HsB[cur * 2048 + (i0loc + m * 16 + r) * 32 + s]);
#pragma unroll
    for (int n = 0; n < 4; ++n)
      bb[n] = *reinterpret_cast<const bf16x8*>(&BsB[cur * 4096 + (j0loc + n * 16 + r) * 32 + s]);
#pragma unroll
    for (int m = 0; m < 2; ++m)
#pragma unroll
      for (int n = 0; n < 4; ++n)
        acc[m][n] = __builtin_amdgcn_mfma_f32_16x16x32_bf16(a[m], bb[n], acc[m][n], 0, 0, 0);
    __syncthreads();
    cur ^= 1;
  }

  float(*buf)[65] = (float(*)[65])((float*)smem + (size_t)wid * 16 * 65);
  int orow = (lane >> 4) * 4;
  int ocol = lane & 15;
  int i0 = iB + i0loc;
  int j0 = jB + j0loc;
  float* ob = outp + (size_t)b * M * KN;
#pragma unroll
  for (int m = 0; m < 2; ++m) {
#pragma unroll
    for (int n = 0; n < 4; ++n)
#pragma unroll
      for (int rr = 0; rr < 4; ++rr) buf[orow + rr][n * 16 + ocol] = fmaxf(acc[m][n][rr], 0.0f);
#pragma unroll
    for (int rr = 0; rr < 4; ++rr) {
      int row = rr * 4 + (lane >> 4);
      float4 v4 = *(const float4*)&buf[row][(lane & 15) * 4];
      *(float4*)(ob + (size_t)(i0 + m * 16 + row) * KN + j0 + (lane & 15) * 4) = v4;
    }
  }
}

// ---------------- reductions ---------------------------------------------
__global__ void bag12_kernel(const float* __restrict__ emb1, const float* __restrict__ mTK,
                             const float* __restrict__ mTD, const float* __restrict__ imp,
                             float* __restrict__ bagk, float* __restrict__ bagd) {
  int c = blockIdx.x, b = blockIdx.y;
  int t = threadIdx.x;
  const float* e = emb1 + ((size_t)b * CMID + c) * KN;
  const float* ir = imp + (size_t)b * KN;
  const float* m1 = mTK + (size_t)b * KN;
  const float* m2 = mTD + (size_t)b * KN;
  float s1 = 0.0f, sd = 0.0f;
  for (int k = t; k < KN; k += 256) {
    float ev = e[k] * ir[k];
    s1 += ev * m1[k];
    sd += ev * m2[k];
  }
  __shared__ float r1[256], r2[256];
  r1[t] = s1;
  r2[t] = sd;
  __syncthreads();
  for (int st = 128; st > 0; st >>= 1) {
    if (t < st) {
      r1[t] += r1[t + st];
      r2[t] += r2[t + st];
    }
    __syncthreads();
  }
  if (t == 0) {
    bagk[(size_t)b * CMID + c] = r1[0] * INV_DS;
    bagd[(size_t)b * CMID + c] = r2[0] * INV_DS;
  }
}

__global__ void bag2_kernel(const float* __restrict__ s2, const float* __restrict__ mTK,
                            const float* __restrict__ imp, float* __restrict__ bag) {
  int o = blockIdx.x, b = blockIdx.y;
  int t = threadIdx.x;
  const float* sr = s2 + ((size_t)b * COUT + o) * KN;
  const float* ir = imp + (size_t)b * KN;
  const float* mr = mTK + (size_t)b * KN;
  float s = 0.0f;
  for (int k = t; k < KN; k += 256) s += sr[k] * mr[k] * ir[k];
  __shared__ float red[256];
  red[t] = s;
  __syncthreads();
  for (int st = 128; st > 0; st >>= 1) {
    if (t < st) red[t] += red[t + st];
    __syncthreads();
  }
  if (t == 0) bag[(size_t)b * COUT + o] = red[0];
}

__global__ void pooled_kernel(const float* __restrict__ x, const float* __restrict__ imp,
                              float* __restrict__ pooled) {
  int c = blockIdx.x, b = blockIdx.y;
  int t = threadIdx.x;
  const float* xr = x + (size_t)(b * CIN + c) * KN;
  const float* ir = imp + (size_t)b * KN;
  float s = 0.0f;
  for (int k = t; k < KN; k += 256) s += xr[k] * ir[k];
  __shared__ float red[256];
  red[t] = s;
  __syncthreads();
  for (int st = 128; st > 0; st >>= 1) {
    if (t < st) red[t] += red[t + st];
    __syncthreads();
  }
  if (t == 0) pooled[(size_t)b * CIN + c] = red[0];
}

__global__ void final_kernel(const float* __restrict__ pooled, const float* __restrict__ bag,
                             const float* __restrict__ id_w, const float* __restrict__ id_b,
                             const float* __restrict__ fc_w, float* __restrict__ out) {
  int b = blockIdx.x;
  int o = threadIdx.x;
  __shared__ float v[COUT];
  float s = id_b[o];
  const float* pr = pooled + (size_t)b * CIN;
  for (int c = 0; c < CIN; ++c) s += pr[c] * id_w[(size_t)c * COUT + o];
  v[o] = bag[(size_t)b * COUT + o] + fmaxf(s, 0.0f);
  __syncthreads();
  if (o < NCLS) {
    float acc = 0.0f;
    for (int oo = 0; oo < COUT; ++oo) acc += v[oo] * fc_w[(size_t)oo * NCLS + o];
    out[(size_t)b * NCLS + o] = acc;
  }
}

// ---------------- launch --------------------------------------------------
extern "C" void kernel_launch(void* const* d_in, const int* in_sizes, int n_in,
                              void* d_out, int out_size, void* d_ws, size_t ws_size,
                              hipStream_t stream) {
  const float* x = (const float*)d_in[0];
  const float* imp = (const float*)d_in[1];
  const float* rnd = (const float*)d_in[2];
  const float* W1 = (const float*)d_in[3];
  const float* W2 = (const float*)d_in[4];
  const float* fc_w = (const float*)d_in[5];
  const float* id_w = (const float*)d_in[6];
  const float* id_b = (const float*)d_in[7];
  float* out = (float*)d_out;
  float* emb1 = out + BN_ * NCLS;
  float* bagk = emb1 + (size_t)BN_ * CMID * KN;
  float* bagd = bagk + (size_t)BN_ * CMID;

  float* w = (float*)d_ws;
  size_t off = 0;
  auto take = [&](size_t n) {
    float* p = w + off;
    off += n;
    return p;
  };
  float* invSumP = take((size_t)BN_ * KN);
  float* invNX = take((size_t)BN_ * KN);
  float* invNE = take((size_t)BN_ * KN);
  float* nrmX = take((size_t)BN_ * KN);
  float* nrmE = take((size_t)BN_ * KN);
  float* topM = take((size_t)BN_ * KN);
  float* mTK = take((size_t)BN_ * KN);
  float* mTD = take((size_t)BN_ * KN);
  float* bag = take((size_t)BN_ * COUT);
  float* pooled = take((size_t)BN_ * CIN);
  ushort* W1T = (ushort*)take((size_t)CMID * CIN / 2);
  ushort* W2T = (ushort*)take((size_t)COUT * CMID / 2);

  const size_t s2_f = (size_t)BN_ * COUT * KN;
  const size_t xg1 = (size_t)CIN * KN / 2;    // per-batch xnT floats
  const size_t hg1 = (size_t)CMID * KN / 2;   // per-batch h floats
  const size_t eg1 = (size_t)CMID * KN / 2;   // per-batch enT floats
  const size_t hg2_1 = (size_t)COUT * KN / 2; // per-batch h2 floats

  size_t budget = ws_size / 4;
  int nb = 1;
  const int cands[6] = {32, 16, 8, 4, 2, 1};
  for (int ci = 0; ci < 6; ++ci) {
    size_t c = cands[ci];
    size_t uA = c * (xg1 + hg1);
    size_t uB = s2_f + c * (eg1 + hg2_1);
    size_t uMax = uA > uB ? uA : uB;
    if (off + uMax + c * (size_t)KN * KN <= budget) {
      nb = (int)c;
      break;
    }
  }
  size_t uA = (size_t)nb * (xg1 + hg1);
  size_t uB = s2_f + (size_t)nb * (eg1 + hg2_1);
  float* U = take(uA > uB ? uA : uB);
  ushort* xnT = (ushort*)U;
  ushort* h = (ushort*)(U + (size_t)nb * xg1);
  ushort* enT = (ushort*)U;
  ushort* h2 = (ushort*)(U + (size_t)nb * eg1);          // group-local
  float* s2 = U + (size_t)nb * (eg1 + hg2_1);
  float* simA = take((size_t)nb * KN * KN);

  maskpsum_kernel<<<dim3(KN / 64, BN_), 256, 0, stream>>>(imp, topM, invSumP);
  masks2_kernel<<<dim3(KN / 64, BN_), 256, 0, stream>>>(rnd, topM, mTK, mTD);
  colnorm_kernel<CIN><<<(BN_ * KN) / 256, 256, 0, stream>>>(x, invNX, nrmX);
  wtrans_kernel<CIN, CMID><<<(CMID * CIN) / 256, 256, 0, stream>>>(W1, W1T);
  wtrans_kernel<CMID, COUT><<<(COUT * CMID) / 256, 256, 0, stream>>>(W2, W2T);

  for (int bs = 0; bs < BN_; bs += nb) {
    xpose_kernel<CIN><<<dim3(KN / 64, CIN / 64, nb), 256, 0, stream>>>(
        x, invNX, (__hip_bfloat16*)xnT, bs);
    linf_kernel<CIN, false><<<dim3(KN / 128, CMID / 64, nb), 256, 0, stream>>>(
        xnT, W1T, nrmX, nullptr, h, CMID, bs);
    simf_kernel<CIN><<<nb * 36, 256, 0, stream>>>(xnT, simA, nb);
    thrfin_kernel<<<dim3(KN / 4, nb), 256, 0, stream>>>(simA, imp, invSumP, bs);
    at_kernel<<<dim3(KN / 64, KN / 64, nb), 256, 0, stream>>>(simA);
    sgemmf_kernel<CMID, true><<<dim3(KN / 128, CMID / 64, nb), 256, 0, stream>>>(h, simA, emb1,
                                                                                 bs);
  }

  colnorm_kernel<CMID><<<(BN_ * KN) / 256, 256, 0, stream>>>(emb1, invNE, nrmE);

  for (int bs = 0; bs < BN_; bs += nb) {
    xpose_kernel<CMID><<<dim3(KN / 64, CMID / 64, nb), 256, 0, stream>>>(
        emb1, invNE, (__hip_bfloat16*)enT, bs);
    linf_kernel<CMID, true><<<dim3(KN / 128, COUT / 64, nb), 256, 0, stream>>>(
        enT, W2T, nrmE, mTK, h2, COUT, bs);
    simf_kernel<CMID><<<nb * 36, 256, 0, stream>>>(enT, simA, nb);
    thrfin_kernel<<<dim3(KN / 4, nb), 256, 0, stream>>>(simA, imp, invSumP, bs);
    at_kernel<<<dim3(KN / 64, KN / 64, nb), 256, 0, stream>>>(simA);
    sgemmf_kernel<COUT, true><<<dim3(KN / 128, COUT / 64, nb), 256, 0, stream>>>(h2, simA, s2,
                                                                                 bs);
  }

  bag12_kernel<<<dim3(CMID, BN_), 256, 0, stream>>>(emb1, mTK, mTD, imp, bagk, bagd);
  bag2_kernel<<<dim3(COUT, BN_), 256, 0, stream>>>(s2, mTK, imp, bag);
  pooled_kernel<<<dim3(CIN, BN_), 256, 0, stream>>>(x, imp, pooled);
  final_kernel<<<BN_, 64, 0, stream>>>(pooled, bag, id_w, id_b, fc_w, out);
}

// Round 30
// 400.888 us; speedup vs baseline: 1.0564x; 1.0564x over previous
//
#include <hip/hip_runtime.h>
#include <hip/hip_bf16.h>
#include <math.h>

#define BN_ 32
#define CIN 512
#define KN 1024
#define CMID 128
#define COUT 64
#define NCLS 5
#define NUM_TOP 205
#define NUM_KEPT 409
#define NUM_DROP 410
#define ADJ_KK 204
#define EPSF 1e-8f
#define INV_DS (1.0f / 0.599609375f)

typedef __bf16 bf16x8 __attribute__((ext_vector_type(8)));
typedef float f32x4 __attribute__((ext_vector_type(4)));

__device__ inline ushort f2bf(float x) {
  union { __hip_bfloat16 b; ushort u; } c;
  c.b = __float2bfloat16(x);
  return c.u;
}

// async global->LDS, 16B per lane (dest = wave-uniform base + lane*16)
__device__ inline void gll16(const ushort* g, ushort* l) {
  __builtin_amdgcn_global_load_lds(
      (const __attribute__((address_space(1))) unsigned int*)g,
      (__attribute__((address_space(3))) unsigned int*)l, 16, 0, 0);
}

// ------- fused top-mask rank + adjP row-sum, 4-way j-split ---------------
__global__ __launch_bounds__(256) void maskpsum_kernel(const float* __restrict__ imp,
                                                       float* __restrict__ topM,
                                                       float* __restrict__ invSumP) {
  int b = blockIdx.y;
  int t = threadIdx.x;
  int io = t >> 2;
  int part = t & 3;
  int i = blockIdx.x * 64 + io;
  __shared__ float im[KN];
  for (int j = t; j < KN; j += 256) im[j] = imp[(size_t)b * KN + j];
  __syncthreads();
  float vi = im[i];
  int j0 = part * 256;
  int rank = 0;
  float s = 0.0f;
#pragma unroll 4
  for (int jj = 0; jj < 256; ++jj) {
    int j = j0 + jj;
    float a = im[j];
    rank += (a > vi || (a == vi && j < i)) ? 1 : 0;
    float d = vi - a;
    s += __expf(-d * d * 0.125f);
  }
  rank += __shfl_xor(rank, 1);
  rank += __shfl_xor(rank, 2);
  s += __shfl_xor(s, 1);
  s += __shfl_xor(s, 2);
  if (part == 0) {
    topM[(size_t)b * KN + i] = (rank < NUM_TOP) ? 1.0f : 0.0f;
    invSumP[(size_t)b * KN + i] = 1.0f / (s + 1.0f + EPSF);
  }
}

// ------- masks stage 2: kept/drop ranks, 4-way j-split (integer-exact) ---
__global__ __launch_bounds__(256) void masks2_kernel(const float* __restrict__ rnd,
                                                     const float* __restrict__ topM,
                                                     float* __restrict__ mTK,
                                                     float* __restrict__ mTD) {
  int b = blockIdx.y;
  int t = threadIdx.x;
  int io = t >> 2;
  int part = t & 3;
  int i = blockIdx.x * 64 + io;
  __shared__ float r1s[KN];
  __shared__ float r2s[KN];
  for (int j = t; j < KN; j += 256) {
    float tv = topM[(size_t)b * KN + j];
    float rv = rnd[(size_t)b * KN + j];
    r1s[j] = (tv > 0.5f) ? -10.0f : rv;
    r2s[j] = (tv > 0.5f) ? 10.0f : rv;
  }
  __syncthreads();
  float v1 = r1s[i];
  float v2 = r2s[i];
  int j0 = part * 256;
  int c1 = 0, c2 = 0;
#pragma unroll 4
  for (int jj = 0; jj < 256; ++jj) {
    int j = j0 + jj;
    float a = r1s[j];
    float bb2 = r2s[j];
    c1 += (a > v1 || (a == v1 && j < i)) ? 1 : 0;
    c2 += (bb2 < v2 || (bb2 == v2 && j < i)) ? 1 : 0;
  }
  c1 += __shfl_xor(c1, 1);
  c1 += __shfl_xor(c1, 2);
  c2 += __shfl_xor(c2, 1);
  c2 += __shfl_xor(c2, 2);
  if (part == 0) {
    int top = topM[(size_t)b * KN + i] > 0.5f;
    mTK[(size_t)b * KN + i] = (top || c1 < NUM_KEPT) ? 1.0f : 0.0f;
    mTD[(size_t)b * KN + i] = (top || c2 < NUM_DROP) ? 1.0f : 0.0f;
  }
}

// ---------------- per-column L2 norm: inv and nrm ------------------------
template <int C>
__global__ void colnorm_kernel(const float* __restrict__ f, float* __restrict__ inv,
                               float* __restrict__ nrm) {
  int idx = blockIdx.x * 256 + threadIdx.x;
  int b = idx >> 10;
  int k = idx & (KN - 1);
  const float* fb = f + (size_t)b * C * KN + k;
  float ss = 0.0f;
  for (int c = 0; c < C; ++c) {
    float v = fb[(size_t)c * KN];
    ss += v * v;
  }
  float n = sqrtf(ss) + EPSF;
  inv[idx] = 1.0f / n;
  nrm[idx] = n;
}

// ------- WT[o][c] = bf16(W[c][o]) for W[R][CC] row-major -----------------
template <int R, int CC>
__global__ __launch_bounds__(256) void wtrans_kernel(const float* __restrict__ W,
                                                     ushort* __restrict__ WT) {
  int idx = blockIdx.x * 256 + threadIdx.x;  // CC*R total
  int o = idx / R;
  int c = idx - o * R;
  WT[(size_t)o * R + c] = f2bf(W[(size_t)c * CC + o]);
}

// ------- transpose+normalize+bf16 into GROUP-LOCAL buffer ---------------
template <int C>
__global__ void xpose_kernel(const float* __restrict__ f, const float* __restrict__ inv,
                             __hip_bfloat16* __restrict__ oT, int bstart) {
  int brel = blockIdx.z;
  int b = bstart + brel;
  int k0 = blockIdx.x * 64;
  int c0 = blockIdx.y * 64;
  __shared__ float t[64][65];
  const float* fb = f + (size_t)b * C * KN;
  int tx = threadIdx.x & 63;
  int ty = threadIdx.x >> 6;
  for (int r = 0; r < 64; r += 4) t[r + ty][tx] = fb[(size_t)(c0 + r + ty) * KN + k0 + tx];
  __syncthreads();
  __hip_bfloat16* ob = oT + (size_t)brel * KN * C;
  for (int r = 0; r < 64; r += 4) {
    int k = r + ty;
    float s = inv[(size_t)b * KN + k0 + k];
    ob[(size_t)(k0 + k) * C + c0 + tx] = __float2bfloat16(t[tx][k] * s);
  }
}

// ---------------- MFMA sim: sim = XnT * XnT^T, bf16 out ------------------
// SYMMETRY: only ti<=tj tiles computed (36 of 64). Off-diagonal tiles also
// write the mirror via a block-level LDS transpose. Mirror stores are
// LANE-contiguous per instruction (32 lanes x 8B = one 256B row) — R29's
// per-thread-sequential layout scattered 8B/lane across 64 lines -> RFO
// fetch storm. XCD swizzle restored (R22-proven).
template <int C>
__global__ __launch_bounds__(256) void simf_kernel(const ushort* __restrict__ xT,
                                                   float* __restrict__ sim, int nb) {
  int f = blockIdx.x;
  int brel, rem;
  if ((nb & 7) == 0) {
    int xcd = f & 7;
    int wdx = f >> 3;  // 0 .. 36*nb/8-1
    brel = xcd * (nb >> 3) + wdx / 36;
    rem = wdx % 36;
  } else {
    brel = f / 36;
    rem = f - brel * 36;
  }
  int ti = 0;
  while (rem >= 8 - ti) {
    rem -= 8 - ti;
    ++ti;
  }
  int tj = ti + rem;
  int t = threadIdx.x;
  int lane = t & 63;
  int wid = t >> 6;
  int iB = ti * 128;
  int jB = tj * 128;
  const ushort* X = xT + (size_t)brel * KN * C;

  __shared__ ushort smem[16384];  // As[2][4096] | Bs[2][4096]; ep aliases base
  ushort* AsB = smem;
  ushort* BsB = smem + 8192;

  int srow = t >> 2;
  int scol = (((t & 3) ^ ((t >> 3) & 3))) * 8;  // pre-swizzled global seg
  int ldst = t * 8;                             // linear LDS dest

  auto stage = [&](int bufi, int c0) {
    gll16(X + (size_t)(iB + srow) * C + c0 + scol, &AsB[bufi * 4096 + ldst]);
    gll16(X + (size_t)(iB + 64 + srow) * C + c0 + scol, &AsB[bufi * 4096 + 2048 + ldst]);
    gll16(X + (size_t)(jB + srow) * C + c0 + scol, &BsB[bufi * 4096 + ldst]);
    gll16(X + (size_t)(jB + 64 + srow) * C + c0 + scol, &BsB[bufi * 4096 + 2048 + ldst]);
  };

  int i0loc = (wid >> 1) * 64;
  int j0loc = (wid & 1) * 64;
  int r = lane & 15;
  int sseg = lane >> 4;

  f32x4 acc[4][4] = {};
  stage(0, 0);
  __syncthreads();
  constexpr int NT = C / 32;
  int cur = 0;
#pragma unroll 2
  for (int ks = 0; ks < NT; ++ks) {
    if (ks + 1 < NT) stage(cur ^ 1, (ks + 1) * 32);
    bf16x8 a[4], bb[4];
#pragma unroll
    for (int m = 0; m < 4; ++m) {
      int row = i0loc + m * 16 + r;
      int off = row * 32 + ((sseg ^ ((row >> 1) & 3)) << 3);
      a[m] = *reinterpret_cast<const bf16x8*>(&AsB[cur * 4096 + off]);
    }
#pragma unroll
    for (int n = 0; n < 4; ++n) {
      int row = j0loc + n * 16 + r;
      int off = row * 32 + ((sseg ^ ((row >> 1) & 3)) << 3);
      bb[n] = *reinterpret_cast<const bf16x8*>(&BsB[cur * 4096 + off]);
    }
#pragma unroll
    for (int m = 0; m < 4; ++m)
#pragma unroll
      for (int n = 0; n < 4; ++n)
        acc[m][n] = __builtin_amdgcn_mfma_f32_16x16x32_bf16(a[m], bb[n], acc[m][n], 0, 0, 0);
    __syncthreads();
    cur ^= 1;
  }

  // primary epilogue: per-wave LDS transpose aliased onto dead staging bufs
  float(*buf)[65] = (float(*)[65])((float*)smem + (size_t)wid * 16 * 65);
  int orow = (lane >> 4) * 4;
  int ocol = lane & 15;
  int i0 = iB + i0loc;
  int j0 = jB + j0loc;
  ushort* simb = (ushort*)sim + (size_t)brel * KN * 2048;
#pragma unroll
  for (int m = 0; m < 4; ++m) {
#pragma unroll
    for (int n = 0; n < 4; ++n)
#pragma unroll
      for (int rr = 0; rr < 4; ++rr) buf[orow + rr][n * 16 + ocol] = acc[m][n][rr];
#pragma unroll
    for (int rr = 0; rr < 4; ++rr) {
      int row = rr * 4 + (lane >> 4);
      float4 v4 = *(const float4*)&buf[row][(lane & 15) * 4];
      ushort4 r4;
      r4.x = f2bf(v4.x);
      r4.y = f2bf(v4.y);
      r4.z = f2bf(v4.z);
      r4.w = f2bf(v4.w);
      *(ushort4*)(simb + (size_t)(i0 + m * 16 + row) * 2048 + j0 + (lane & 15) * 4) = r4;
    }
  }

  // mirror pass: whole-block 128x128 bf16 transpose in smem, then stores
  // with 32 adjacent lanes covering each 256B row (full-line, coalesced).
  if (iB != jB) {
    __syncthreads();  // all waves done with primary epilogue bufs
    ushort* Tm = smem;  // [128][128] ushort = 32KB, XOR-swz on 8B units
#pragma unroll
    for (int m = 0; m < 4; ++m)
#pragma unroll
      for (int n = 0; n < 4; ++n) {
        int cu = ((i0loc + m * 16) >> 2) + (lane >> 4);  // data col unit (0..31)
        int row = j0loc + n * 16 + (lane & 15);
        int u = cu ^ (row & 15);
        ushort4 val;
        val.x = f2bf(acc[m][n][0]);
        val.y = f2bf(acc[m][n][1]);
        val.z = f2bf(acc[m][n][2]);
        val.w = f2bf(acc[m][n][3]);
        *(ushort4*)&Tm[row * 128 + u * 4] = val;
      }
    __syncthreads();
    int colu = t & 31;  // 8B unit within row
    int rb = t >> 5;    // 8 rows per iteration
#pragma unroll
    for (int it = 0; it < 16; ++it) {
      int row = it * 8 + rb;
      int u = colu ^ (row & 15);
      *(ushort4*)(simb + (size_t)(jB + row) * 2048 + iB + colu * 4) =
          *(const ushort4*)&Tm[row * 128 + u * 4];
    }
  }
}

// ------- fused per-wave threshold select + finalize (bf16 sim) -----------
__global__ __launch_bounds__(256) void thrfin_kernel(float* __restrict__ A,
                                                     const float* __restrict__ imp,
                                                     const float* __restrict__ invSumP,
                                                     int bstart) {
  int brel = blockIdx.y;
  int b = bstart + brel;
  int wid = threadIdx.x >> 6;
  int lane = threadIdx.x & 63;
  int i = blockIdx.x * 4 + wid;
  ushort* row = (ushort*)A + ((size_t)brel * KN + i) * 2048;
  __shared__ float im[KN];
  ((float4*)im)[threadIdx.x] = ((const float4*)(imp + (size_t)b * KN))[threadIdx.x];
  __syncthreads();

  ushort4 v[4];
  unsigned key[16];
#pragma unroll
  for (int q = 0; q < 4; ++q) v[q] = ((const ushort4*)row)[lane + 64 * q];
#pragma unroll
  for (int q = 0; q < 4; ++q) {
    const ushort* pv = (const ushort*)&v[q];
#pragma unroll
    for (int e = 0; e < 4; ++e) {
      ushort u = pv[e];
      key[q * 4 + e] = (u & 0x8000u) ? (unsigned)(ushort)~u : (unsigned)(u | 0x8000u);
    }
  }
  unsigned tk = 0u;
#pragma unroll 1
  for (int bit = 15; bit >= 0; --bit) {
    unsigned cand = tk | (1u << bit);
    int c = 0;
#pragma unroll
    for (int e = 0; e < 8; ++e)
      c += (int)__popcll(__ballot(key[e] >= cand));
    int cl = 0;
#pragma unroll
    for (int e = 8; e < 16; ++e) cl += (key[e] >= cand) ? 1 : 0;
#pragma unroll
    for (int off = 32; off > 0; off >>= 1) cl += __shfl_xor(cl, off);
    c += cl;
    if (c >= ADJ_KK) tk = cand;
  }
  float m[16];
  float s = 0.0f;
#pragma unroll
  for (int q = 0; q < 4; ++q) {
    const ushort* pv = (const ushort*)&v[q];
#pragma unroll
    for (int e = 0; e < 4; ++e) {
      float val = __uint_as_float(((unsigned)pv[e]) << 16);
      float mv = (key[q * 4 + e] >= tk) ? val : 0.0f;
      m[q * 4 + e] = mv;
      s += mv;
    }
  }
#pragma unroll
  for (int off = 32; off > 0; off >>= 1) s += __shfl_xor(s, off);
  float invF = 1.0f / (s + 1.0f + EPSF);
  float vi = im[i];
  float invP = invSumP[(size_t)b * KN + i];
#pragma unroll
  for (int q = 0; q < 4; ++q) {
    float4 iv = ((const float4*)im)[lane + 64 * q];
    const float* ip = (const float*)&iv;
    ushort4 r;
    ushort* rp = (ushort*)&r;
    int colb = 4 * lane + 256 * q;
#pragma unroll
    for (int e = 0; e < 4; ++e) {
      float diag = (colb + e == i) ? 1.0f : 0.0f;
      float d = vi - ip[e];
      rp[e] = f2bf((m[q * 4 + e] + diag) * invF + (__expf(-d * d * 0.125f) + diag) * invP);
    }
    ((ushort4*)row)[lane + 64 * q] = r;
  }
}

// ------- bf16 transpose INTO sim rows' back halves -----------------------
__global__ __launch_bounds__(256) void at_kernel(float* __restrict__ Asim) {
  int brel = blockIdx.z;
  int k0 = blockIdx.x * 64;
  int j0 = blockIdx.y * 64;
  __shared__ ushort t[64][68];
  ushort* Ab = (ushort*)(Asim + (size_t)brel * KN * KN);
  int g = threadIdx.x & 15;
  int r = threadIdx.x >> 4;
#pragma unroll
  for (int p = 0; p < 4; ++p) {
    int row = p * 16 + r;
    *(ushort4*)&t[row][g * 4] =
        *(const ushort4*)&Ab[(size_t)(k0 + row) * 2048 + j0 + g * 4];
  }
  __syncthreads();
#pragma unroll
  for (int p = 0; p < 4; ++p) {
    int j = p * 16 + r;
    ushort4 v;
    v.x = t[g * 4 + 0][j];
    v.y = t[g * 4 + 1][j];
    v.z = t[g * 4 + 2][j];
    v.w = t[g * 4 + 3][j];
    *(ushort4*)&Ab[(size_t)(j0 + j) * 2048 + 1024 + k0 + g * 4] = v;
  }
}

// ---------------- MFMA linear: hg[brel,o,k] = fac(k)*sum_c WT[o,c]*fT[k,c]
// fac = nrm[k] (layer 1) or mTK[k]*INV_DS*nrm[k] (layer 2).
// Epilogue aliased onto dead staging buffers.
template <int C, bool MASK>
__global__ __launch_bounds__(256) void linf_kernel(const ushort* __restrict__ xg,
                                                   const ushort* __restrict__ WT,
                                                   const float* __restrict__ nrm,
                                                   const float* __restrict__ mTK,
                                                   ushort* __restrict__ hg, int M,
                                                   int bstart) {
  int brel = blockIdx.z;
  int b = bstart + brel;
  int t = threadIdx.x;
  int lane = t & 63;
  int wid = t >> 6;
  int iB = blockIdx.y * 64;
  int jB = blockIdx.x * 128;
  const ushort* xb = xg + (size_t)brel * KN * C;

  __shared__ ushort smem[12288];  // Hs[2][2048] | Bs[2][4096]; ep aliases base
  ushort* HsB = smem;
  ushort* BsB = smem + 4096;

  int srow = t >> 2;
  int scol = (t & 3) * 8;
  int ldst = t * 8;

  auto stage = [&](int bufi, int c0) {
    gll16(WT + (size_t)(iB + srow) * C + c0 + scol, &HsB[bufi * 2048 + ldst]);
    gll16(xb + (size_t)(jB + srow) * C + c0 + scol, &BsB[bufi * 4096 + ldst]);
    gll16(xb + (size_t)(jB + 64 + srow) * C + c0 + scol, &BsB[bufi * 4096 + 2048 + ldst]);
  };

  int i0loc = (wid >> 1) * 32;
  int j0loc = (wid & 1) * 64;
  int r = lane & 15;
  int s = (lane >> 4) * 8;

  f32x4 acc[2][4] = {};
  stage(0, 0);
  __syncthreads();
  int cur = 0;
#pragma unroll 2
  for (int ks = 0; ks < C / 32; ++ks) {
    if (ks + 1 < C / 32) stage(cur ^ 1, (ks + 1) * 32);
    bf16x8 a[2], bb[4];
#pragma unroll
    for (int m = 0; m < 2; ++m)
      a[m] = *reinterpret_cast<const bf16x8*>(&HsB[cur * 2048 + (i0loc + m * 16 + r) * 32 + s]);
#pragma unroll
    for (int n = 0; n < 4; ++n)
      bb[n] = *reinterpret_cast<const bf16x8*>(&BsB[cur * 4096 + (j0loc + n * 16 + r) * 32 + s]);
#pragma unroll
    for (int m = 0; m < 2; ++m)
#pragma unroll
      for (int n = 0; n < 4; ++n)
        acc[m][n] = __builtin_amdgcn_mfma_f32_16x16x32_bf16(a[m], bb[n], acc[m][n], 0, 0, 0);
    __syncthreads();
    cur ^= 1;
  }

  float(*buf)[65] = (float(*)[65])((float*)smem + (size_t)wid * 16 * 65);
  int orow = (lane >> 4) * 4;
  int ocol = lane & 15;
  int i0 = iB + i0loc;
  int j0 = jB + j0loc;
#pragma unroll
  for (int m = 0; m < 2; ++m) {
#pragma unroll
    for (int n = 0; n < 4; ++n)
#pragma unroll
      for (int rr = 0; rr < 4; ++rr) buf[orow + rr][n * 16 + ocol] = acc[m][n][rr];
#pragma unroll
    for (int rr = 0; rr < 4; ++rr) {
      int row = rr * 4 + (lane >> 4);
      int kk = j0 + (lane & 15) * 4;
      float4 v4 = *(const float4*)&buf[row][(lane & 15) * 4];
      float4 nv = *(const float4*)(nrm + (size_t)b * KN + kk);
      float f0 = nv.x, f1 = nv.y, f2 = nv.z, f3 = nv.w;
      if (MASK) {
        float4 mv = *(const float4*)(mTK + (size_t)b * KN + kk);
        f0 *= mv.x * INV_DS;
        f1 *= mv.y * INV_DS;
        f2 *= mv.z * INV_DS;
        f3 *= mv.w * INV_DS;
      }
      ushort4 r4;
      r4.x = f2bf(v4.x * f0);
      r4.y = f2bf(v4.y * f1);
      r4.z = f2bf(v4.z * f2);
      r4.w = f2bf(v4.w * f3);
      *(ushort4*)(hg + ((size_t)brel * M + i0 + m * 16 + row) * KN + kk) = r4;
    }
  }
}

// ---------------- MFMA s = relu(h @ A), At read from sim back halves -----
// Epilogue aliased onto dead staging buffers (24KB LDS total).
template <int M, bool LOCAL>
__global__ __launch_bounds__(256) void sgemmf_kernel(const ushort* __restrict__ hB,
                                                     const float* __restrict__ Asim,
                                                     float* __restrict__ outp, int bstart) {
  int brel = blockIdx.z;
  int b = bstart + brel;
  int t = threadIdx.x;
  int lane = t & 63;
  int wid = t >> 6;
  int iB = blockIdx.y * 64;
  int jB = blockIdx.x * 128;
  const ushort* hb = hB + (size_t)(LOCAL ? brel : b) * M * KN;
  const ushort* Ab = (const ushort*)(Asim + (size_t)brel * KN * KN);

  __shared__ ushort smem[12288];  // Hs[2][2048] | Bs[2][4096]; ep aliases base
  ushort* HsB = smem;
  ushort* BsB = smem + 4096;

  int srow = t >> 2;
  int scol = (t & 3) * 8;
  int ldst = t * 8;

  auto stage = [&](int bufi, int k0) {
    gll16(hb + (size_t)(iB + srow) * KN + k0 + scol, &HsB[bufi * 2048 + ldst]);
    gll16(Ab + (size_t)(jB + srow) * 2048 + 1024 + k0 + scol, &BsB[bufi * 4096 + ldst]);
    gll16(Ab + (size_t)(jB + 64 + srow) * 2048 + 1024 + k0 + scol,
          &BsB[bufi * 4096 + 2048 + ldst]);
  };

  int i0loc = (wid >> 1) * 32;
  int j0loc = (wid & 1) * 64;
  int r = lane & 15;
  int s = (lane >> 4) * 8;

  f32x4 acc[2][4] = {};
  stage(0, 0);
  __syncthreads();
  int cur = 0;
#pragma unroll 2
  for (int ks = 0; ks < KN / 32; ++ks) {
    if (ks + 1 < KN / 32) stage(cur ^ 1, (ks + 1) * 32);
    bf16x8 a[2], bb[4];
#pragma unroll
    for (int m = 0; m < 2; ++m)
      a[m] = *reinterpret_cast<const bf16x8*>(&HsB[cur * 2048 + (i0loc + m * 16 + r) * 32 + s]);
#pragma unroll
    for (int n = 0; n < 4; ++n)
      bb[n] = *reinterpret_cast<const bf16x8*>(&BsB[cur * 4096 + (j0loc + n * 16 + r) * 32 + s]);
#pragma unroll
    for (int m = 0; m < 2; ++m)
#pragma unroll
      for (int n = 0; n < 4; ++n)
        acc[m][n] = __builtin_amdgcn_mfma_f32_16x16x32_bf16(a[m], bb[n], acc[m][n], 0, 0, 0);
    __syncthreads();
    cur ^= 1;
  }

  float(*buf)[65] = (float(*)[65])((float*)smem + (size_t)wid * 16 * 65);
  int orow = (lane >> 4) * 4;
  int ocol = lane & 15;
  int i0 = iB + i0loc;
  int j0 = jB + j0loc;
  float* ob = outp + (size_t)b * M * KN;
#pragma unroll
  for (int m = 0; m < 2; ++m) {
#pragma unroll
    for (int n = 0; n < 4; ++n)
#pragma unroll
      for (int rr = 0; rr < 4; ++rr) buf[orow + rr][n * 16 + ocol] = fmaxf(acc[m][n][rr], 0.0f);
#pragma unroll
    for (int rr = 0; rr < 4; ++rr) {
      int row = rr * 4 + (lane >> 4);
      float4 v4 = *(const float4*)&buf[row][(lane & 15) * 4];
      *(float4*)(ob + (size_t)(i0 + m * 16 + row) * KN + j0 + (lane & 15) * 4) = v4;
    }
  }
}

// ---------------- reductions ---------------------------------------------
__global__ void bag12_kernel(const float* __restrict__ emb1, const float* __restrict__ mTK,
                             const float* __restrict__ mTD, const float* __restrict__ imp,
                             float* __restrict__ bagk, float* __restrict__ bagd) {
  int c = blockIdx.x, b = blockIdx.y;
  int t = threadIdx.x;
  const float* e = emb1 + ((size_t)b * CMID + c) * KN;
  const float* ir = imp + (size_t)b * KN;
  const float* m1 = mTK + (size_t)b * KN;
  const float* m2 = mTD + (size_t)b * KN;
  float s1 = 0.0f, sd = 0.0f;
  for (int k = t; k < KN; k += 256) {
    float ev = e[k] * ir[k];
    s1 += ev * m1[k];
    sd += ev * m2[k];
  }
  __shared__ float r1[256], r2[256];
  r1[t] = s1;
  r2[t] = sd;
  __syncthreads();
  for (int st = 128; st > 0; st >>= 1) {
    if (t < st) {
      r1[t] += r1[t + st];
      r2[t] += r2[t + st];
    }
    __syncthreads();
  }
  if (t == 0) {
    bagk[(size_t)b * CMID + c] = r1[0] * INV_DS;
    bagd[(size_t)b * CMID + c] = r2[0] * INV_DS;
  }
}

__global__ void bag2_kernel(const float* __restrict__ s2, const float* __restrict__ mTK,
                            const float* __restrict__ imp, float* __restrict__ bag) {
  int o = blockIdx.x, b = blockIdx.y;
  int t = threadIdx.x;
  const float* sr = s2 + ((size_t)b * COUT + o) * KN;
  const float* ir = imp + (size_t)b * KN;
  const float* mr = mTK + (size_t)b * KN;
  float s = 0.0f;
  for (int k = t; k < KN; k += 256) s += sr[k] * mr[k] * ir[k];
  __shared__ float red[256];
  red[t] = s;
  __syncthreads();
  for (int st = 128; st > 0; st >>= 1) {
    if (t < st) red[t] += red[t + st];
    __syncthreads();
  }
  if (t == 0) bag[(size_t)b * COUT + o] = red[0];
}

__global__ void pooled_kernel(const float* __restrict__ x, const float* __restrict__ imp,
                              float* __restrict__ pooled) {
  int c = blockIdx.x, b = blockIdx.y;
  int t = threadIdx.x;
  const float* xr = x + (size_t)(b * CIN + c) * KN;
  const float* ir = imp + (size_t)b * KN;
  float s = 0.0f;
  for (int k = t; k < KN; k += 256) s += xr[k] * ir[k];
  __shared__ float red[256];
  red[t] = s;
  __syncthreads();
  for (int st = 128; st > 0; st >>= 1) {
    if (t < st) red[t] += red[t + st];
    __syncthreads();
  }
  if (t == 0) pooled[(size_t)b * CIN + c] = red[0];
}

__global__ void final_kernel(const float* __restrict__ pooled, const float* __restrict__ bag,
                             const float* __restrict__ id_w, const float* __restrict__ id_b,
                             const float* __restrict__ fc_w, float* __restrict__ out) {
  int b = blockIdx.x;
  int o = threadIdx.x;
  __shared__ float v[COUT];
  float s = id_b[o];
  const float* pr = pooled + (size_t)b * CIN;
  for (int c = 0; c < CIN; ++c) s += pr[c] * id_w[(size_t)c * COUT + o];
  v[o] = bag[(size_t)b * COUT + o] + fmaxf(s, 0.0f);
  __syncthreads();
  if (o < NCLS) {
    float acc = 0.0f;
    for (int oo = 0; oo < COUT; ++oo) acc += v[oo] * fc_w[(size_t)oo * NCLS + o];
    out[(size_t)b * NCLS + o] = acc;
  }
}

// ---------------- launch --------------------------------------------------
extern "C" void kernel_launch(void* const* d_in, const int* in_sizes, int n_in,
                              void* d_out, int out_size, void* d_ws, size_t ws_size,
                              hipStream_t stream) {
  const float* x = (const float*)d_in[0];
  const float* imp = (const float*)d_in[1];
  const float* rnd = (const float*)d_in[2];
  const float* W1 = (const float*)d_in[3];
  const float* W2 = (const float*)d_in[4];
  const float* fc_w = (const float*)d_in[5];
  const float* id_w = (const float*)d_in[6];
  const float* id_b = (const float*)d_in[7];
  float* out = (float*)d_out;
  float* emb1 = out + BN_ * NCLS;
  float* bagk = emb1 + (size_t)BN_ * CMID * KN;
  float* bagd = bagk + (size_t)BN_ * CMID;

  float* w = (float*)d_ws;
  size_t off = 0;
  auto take = [&](size_t n) {
    float* p = w + off;
    off += n;
    return p;
  };
  float* invSumP = take((size_t)BN_ * KN);
  float* invNX = take((size_t)BN_ * KN);
  float* invNE = take((size_t)BN_ * KN);
  float* nrmX = take((size_t)BN_ * KN);
  float* nrmE = take((size_t)BN_ * KN);
  float* topM = take((size_t)BN_ * KN);
  float* mTK = take((size_t)BN_ * KN);
  float* mTD = take((size_t)BN_ * KN);
  float* bag = take((size_t)BN_ * COUT);
  float* pooled = take((size_t)BN_ * CIN);
  ushort* W1T = (ushort*)take((size_t)CMID * CIN / 2);
  ushort* W2T = (ushort*)take((size_t)COUT * CMID / 2);

  const size_t s2_f = (size_t)BN_ * COUT * KN;
  const size_t xg1 = (size_t)CIN * KN / 2;    // per-batch xnT floats
  const size_t hg1 = (size_t)CMID * KN / 2;   // per-batch h floats
  const size_t eg1 = (size_t)CMID * KN / 2;   // per-batch enT floats
  const size_t hg2_1 = (size_t)COUT * KN / 2; // per-batch h2 floats

  size_t budget = ws_size / 4;
  int nb = 1;
  const int cands[6] = {32, 16, 8, 4, 2, 1};
  for (int ci = 0; ci < 6; ++ci) {
    size_t c = cands[ci];
    size_t uA = c * (xg1 + hg1);
    size_t uB = s2_f + c * (eg1 + hg2_1);
    size_t uMax = uA > uB ? uA : uB;
    if (off + uMax + c * (size_t)KN * KN <= budget) {
      nb = (int)c;
      break;
    }
  }
  size_t uA = (size_t)nb * (xg1 + hg1);
  size_t uB = s2_f + (size_t)nb * (eg1 + hg2_1);
  float* U = take(uA > uB ? uA : uB);
  ushort* xnT = (ushort*)U;
  ushort* h = (ushort*)(U + (size_t)nb * xg1);
  ushort* enT = (ushort*)U;
  ushort* h2 = (ushort*)(U + (size_t)nb * eg1);          // group-local
  float* s2 = U + (size_t)nb * (eg1 + hg2_1);
  float* simA = take((size_t)nb * KN * KN);

  maskpsum_kernel<<<dim3(KN / 64, BN_), 256, 0, stream>>>(imp, topM, invSumP);
  masks2_kernel<<<dim3(KN / 64, BN_), 256, 0, stream>>>(rnd, topM, mTK, mTD);
  colnorm_kernel<CIN><<<(BN_ * KN) / 256, 256, 0, stream>>>(x, invNX, nrmX);
  wtrans_kernel<CIN, CMID><<<(CMID * CIN) / 256, 256, 0, stream>>>(W1, W1T);
  wtrans_kernel<CMID, COUT><<<(COUT * CMID) / 256, 256, 0, stream>>>(W2, W2T);

  for (int bs = 0; bs < BN_; bs += nb) {
    xpose_kernel<CIN><<<dim3(KN / 64, CIN / 64, nb), 256, 0, stream>>>(
        x, invNX, (__hip_bfloat16*)xnT, bs);
    linf_kernel<CIN, false><<<dim3(KN / 128, CMID / 64, nb), 256, 0, stream>>>(
        xnT, W1T, nrmX, nullptr, h, CMID, bs);
    simf_kernel<CIN><<<nb * 36, 256, 0, stream>>>(xnT, simA, nb);
    thrfin_kernel<<<dim3(KN / 4, nb), 256, 0, stream>>>(simA, imp, invSumP, bs);
    at_kernel<<<dim3(KN / 64, KN / 64, nb), 256, 0, stream>>>(simA);
    sgemmf_kernel<CMID, true><<<dim3(KN / 128, CMID / 64, nb), 256, 0, stream>>>(h, simA, emb1,
                                                                                 bs);
  }

  colnorm_kernel<CMID><<<(BN_ * KN) / 256, 256, 0, stream>>>(emb1, invNE, nrmE);

  for (int bs = 0; bs < BN_; bs += nb) {
    xpose_kernel<CMID><<<dim3(KN / 64, CMID / 64, nb), 256, 0, stream>>>(
        emb1, invNE, (__hip_bfloat16*)enT, bs);
    linf_kernel<CMID, true><<<dim3(KN / 128, COUT / 64, nb), 256, 0, stream>>>(
        enT, W2T, nrmE, mTK, h2, COUT, bs);
    simf_kernel<CMID><<<nb * 36, 256, 0, stream>>>(enT, simA, nb);
    thrfin_kernel<<<dim3(KN / 4, nb), 256, 0, stream>>>(simA, imp, invSumP, bs);
    at_kernel<<<dim3(KN / 64, KN / 64, nb), 256, 0, stream>>>(simA);
    sgemmf_kernel<COUT, true><<<dim3(KN / 128, COUT / 64, nb), 256, 0, stream>>>(h2, simA, s2,
                                                                                 bs);
  }

  bag12_kernel<<<dim3(CMID, BN_), 256, 0, stream>>>(emb1, mTK, mTD, imp, bagk, bagd);
  bag2_kernel<<<dim3(COUT, BN_), 256, 0, stream>>>(s2, mTK, imp, bag);
  pooled_kernel<<<dim3(CIN, BN_), 256, 0, stream>>>(x, imp, pooled);
  final_kernel<<<BN_, 64, 0, stream>>>(pooled, bag, id_w, id_b, fc_w, out);
}

// Round 31
// 385.006 us; speedup vs baseline: 1.1000x; 1.0413x over previous
//
#include <hip/hip_runtime.h>
#include <hip/hip_bf16.h>
#include <math.h>

#define BN_ 32
#define CIN 512
#define KN 1024
#define CMID 128
#define COUT 64
#define NCLS 5
#define NUM_TOP 205
#define NUM_KEPT 409
#define NUM_DROP 410
#define ADJ_KK 204
#define EPSF 1e-8f
#define INV_DS (1.0f / 0.599609375f)

typedef __bf16 bf16x8 __attribute__((ext_vector_type(8)));
typedef float f32x4 __attribute__((ext_vector_type(4)));

__device__ inline ushort f2bf(float x) {
  union { __hip_bfloat16 b; ushort u; } c;
  c.b = __float2bfloat16(x);
  return c.u;
}

// async global->LDS, 16B per lane (dest = wave-uniform base + lane*16)
__device__ inline void gll16(const ushort* g, ushort* l) {
  __builtin_amdgcn_global_load_lds(
      (const __attribute__((address_space(1))) unsigned int*)g,
      (__attribute__((address_space(3))) unsigned int*)l, 16, 0, 0);
}

// ------- fused top-mask rank + adjP row-sum, 4-way j-split ---------------
__global__ __launch_bounds__(256) void maskpsum_kernel(const float* __restrict__ imp,
                                                       float* __restrict__ topM,
                                                       float* __restrict__ invSumP) {
  int b = blockIdx.y;
  int t = threadIdx.x;
  int io = t >> 2;
  int part = t & 3;
  int i = blockIdx.x * 64 + io;
  __shared__ float im[KN];
  for (int j = t; j < KN; j += 256) im[j] = imp[(size_t)b * KN + j];
  __syncthreads();
  float vi = im[i];
  int j0 = part * 256;
  int rank = 0;
  float s = 0.0f;
#pragma unroll 4
  for (int jj = 0; jj < 256; ++jj) {
    int j = j0 + jj;
    float a = im[j];
    rank += (a > vi || (a == vi && j < i)) ? 1 : 0;
    float d = vi - a;
    s += __expf(-d * d * 0.125f);
  }
  rank += __shfl_xor(rank, 1);
  rank += __shfl_xor(rank, 2);
  s += __shfl_xor(s, 1);
  s += __shfl_xor(s, 2);
  if (part == 0) {
    topM[(size_t)b * KN + i] = (rank < NUM_TOP) ? 1.0f : 0.0f;
    invSumP[(size_t)b * KN + i] = 1.0f / (s + 1.0f + EPSF);
  }
}

// ------- masks stage 2: kept/drop ranks, 4-way j-split (integer-exact) ---
__global__ __launch_bounds__(256) void masks2_kernel(const float* __restrict__ rnd,
                                                     const float* __restrict__ topM,
                                                     float* __restrict__ mTK,
                                                     float* __restrict__ mTD) {
  int b = blockIdx.y;
  int t = threadIdx.x;
  int io = t >> 2;
  int part = t & 3;
  int i = blockIdx.x * 64 + io;
  __shared__ float r1s[KN];
  __shared__ float r2s[KN];
  for (int j = t; j < KN; j += 256) {
    float tv = topM[(size_t)b * KN + j];
    float rv = rnd[(size_t)b * KN + j];
    r1s[j] = (tv > 0.5f) ? -10.0f : rv;
    r2s[j] = (tv > 0.5f) ? 10.0f : rv;
  }
  __syncthreads();
  float v1 = r1s[i];
  float v2 = r2s[i];
  int j0 = part * 256;
  int c1 = 0, c2 = 0;
#pragma unroll 4
  for (int jj = 0; jj < 256; ++jj) {
    int j = j0 + jj;
    float a = r1s[j];
    float bb2 = r2s[j];
    c1 += (a > v1 || (a == v1 && j < i)) ? 1 : 0;
    c2 += (bb2 < v2 || (bb2 == v2 && j < i)) ? 1 : 0;
  }
  c1 += __shfl_xor(c1, 1);
  c1 += __shfl_xor(c1, 2);
  c2 += __shfl_xor(c2, 1);
  c2 += __shfl_xor(c2, 2);
  if (part == 0) {
    int top = topM[(size_t)b * KN + i] > 0.5f;
    mTK[(size_t)b * KN + i] = (top || c1 < NUM_KEPT) ? 1.0f : 0.0f;
    mTD[(size_t)b * KN + i] = (top || c2 < NUM_DROP) ? 1.0f : 0.0f;
  }
}

// ---------------- per-column L2 norm: inv and nrm ------------------------
template <int C>
__global__ void colnorm_kernel(const float* __restrict__ f, float* __restrict__ inv,
                               float* __restrict__ nrm) {
  int idx = blockIdx.x * 256 + threadIdx.x;
  int b = idx >> 10;
  int k = idx & (KN - 1);
  const float* fb = f + (size_t)b * C * KN + k;
  float ss = 0.0f;
  for (int c = 0; c < C; ++c) {
    float v = fb[(size_t)c * KN];
    ss += v * v;
  }
  float n = sqrtf(ss) + EPSF;
  inv[idx] = 1.0f / n;
  nrm[idx] = n;
}

// ------- WT[o][c] = bf16(W[c][o]) for W[R][CC] row-major -----------------
template <int R, int CC>
__global__ __launch_bounds__(256) void wtrans_kernel(const float* __restrict__ W,
                                                     ushort* __restrict__ WT) {
  int idx = blockIdx.x * 256 + threadIdx.x;  // CC*R total
  int o = idx / R;
  int c = idx - o * R;
  WT[(size_t)o * R + c] = f2bf(W[(size_t)c * CC + o]);
}

// ------- transpose+normalize+bf16 into GROUP-LOCAL buffer ---------------
template <int C>
__global__ void xpose_kernel(const float* __restrict__ f, const float* __restrict__ inv,
                             __hip_bfloat16* __restrict__ oT, int bstart) {
  int brel = blockIdx.z;
  int b = bstart + brel;
  int k0 = blockIdx.x * 64;
  int c0 = blockIdx.y * 64;
  __shared__ float t[64][65];
  const float* fb = f + (size_t)b * C * KN;
  int tx = threadIdx.x & 63;
  int ty = threadIdx.x >> 6;
  for (int r = 0; r < 64; r += 4) t[r + ty][tx] = fb[(size_t)(c0 + r + ty) * KN + k0 + tx];
  __syncthreads();
  __hip_bfloat16* ob = oT + (size_t)brel * KN * C;
  for (int r = 0; r < 64; r += 4) {
    int k = r + ty;
    float s = inv[(size_t)b * KN + k0 + k];
    ob[(size_t)(k0 + k) * C + c0 + tx] = __float2bfloat16(t[tx][k] * s);
  }
}

// ---------------- MFMA sim: sim = XnT * XnT^T, bf16 out ------------------
// SYMMETRY: only ti<=tj tiles computed (36 of 64). Off-diagonal tiles also
// write the mirror via a block-level LDS transpose with lane-contiguous
// full-row stores. XCD swizzle on batch index (R22/R30-proven).
template <int C>
__global__ __launch_bounds__(256) void simf_kernel(const ushort* __restrict__ xT,
                                                   float* __restrict__ sim, int nb) {
  int f = blockIdx.x;
  int brel, rem;
  if ((nb & 7) == 0) {
    int xcd = f & 7;
    int wdx = f >> 3;  // 0 .. 36*nb/8-1
    brel = xcd * (nb >> 3) + wdx / 36;
    rem = wdx % 36;
  } else {
    brel = f / 36;
    rem = f - brel * 36;
  }
  int ti = 0;
  while (rem >= 8 - ti) {
    rem -= 8 - ti;
    ++ti;
  }
  int tj = ti + rem;
  int t = threadIdx.x;
  int lane = t & 63;
  int wid = t >> 6;
  int iB = ti * 128;
  int jB = tj * 128;
  const ushort* X = xT + (size_t)brel * KN * C;

  __shared__ ushort smem[16384];  // As[2][4096] | Bs[2][4096]; ep aliases base
  ushort* AsB = smem;
  ushort* BsB = smem + 8192;

  int srow = t >> 2;
  int scol = (((t & 3) ^ ((t >> 3) & 3))) * 8;  // pre-swizzled global seg
  int ldst = t * 8;                             // linear LDS dest

  auto stage = [&](int bufi, int c0) {
    gll16(X + (size_t)(iB + srow) * C + c0 + scol, &AsB[bufi * 4096 + ldst]);
    gll16(X + (size_t)(iB + 64 + srow) * C + c0 + scol, &AsB[bufi * 4096 + 2048 + ldst]);
    gll16(X + (size_t)(jB + srow) * C + c0 + scol, &BsB[bufi * 4096 + ldst]);
    gll16(X + (size_t)(jB + 64 + srow) * C + c0 + scol, &BsB[bufi * 4096 + 2048 + ldst]);
  };

  int i0loc = (wid >> 1) * 64;
  int j0loc = (wid & 1) * 64;
  int r = lane & 15;
  int sseg = lane >> 4;

  f32x4 acc[4][4] = {};
  stage(0, 0);
  __syncthreads();
  constexpr int NT = C / 32;
  int cur = 0;
#pragma unroll 2
  for (int ks = 0; ks < NT; ++ks) {
    if (ks + 1 < NT) stage(cur ^ 1, (ks + 1) * 32);
    bf16x8 a[4], bb[4];
#pragma unroll
    for (int m = 0; m < 4; ++m) {
      int row = i0loc + m * 16 + r;
      int off = row * 32 + ((sseg ^ ((row >> 1) & 3)) << 3);
      a[m] = *reinterpret_cast<const bf16x8*>(&AsB[cur * 4096 + off]);
    }
#pragma unroll
    for (int n = 0; n < 4; ++n) {
      int row = j0loc + n * 16 + r;
      int off = row * 32 + ((sseg ^ ((row >> 1) & 3)) << 3);
      bb[n] = *reinterpret_cast<const bf16x8*>(&BsB[cur * 4096 + off]);
    }
#pragma unroll
    for (int m = 0; m < 4; ++m)
#pragma unroll
      for (int n = 0; n < 4; ++n)
        acc[m][n] = __builtin_amdgcn_mfma_f32_16x16x32_bf16(a[m], bb[n], acc[m][n], 0, 0, 0);
    __syncthreads();
    cur ^= 1;
  }

  // primary epilogue: per-wave LDS transpose aliased onto dead staging bufs
  float(*buf)[65] = (float(*)[65])((float*)smem + (size_t)wid * 16 * 65);
  int orow = (lane >> 4) * 4;
  int ocol = lane & 15;
  int i0 = iB + i0loc;
  int j0 = jB + j0loc;
  ushort* simb = (ushort*)sim + (size_t)brel * KN * 2048;
#pragma unroll
  for (int m = 0; m < 4; ++m) {
#pragma unroll
    for (int n = 0; n < 4; ++n)
#pragma unroll
      for (int rr = 0; rr < 4; ++rr) buf[orow + rr][n * 16 + ocol] = acc[m][n][rr];
#pragma unroll
    for (int rr = 0; rr < 4; ++rr) {
      int row = rr * 4 + (lane >> 4);
      float4 v4 = *(const float4*)&buf[row][(lane & 15) * 4];
      ushort4 r4;
      r4.x = f2bf(v4.x);
      r4.y = f2bf(v4.y);
      r4.z = f2bf(v4.z);
      r4.w = f2bf(v4.w);
      *(ushort4*)(simb + (size_t)(i0 + m * 16 + row) * 2048 + j0 + (lane & 15) * 4) = r4;
    }
  }

  // mirror pass: whole-block 128x128 bf16 transpose in smem, then stores
  // with 32 adjacent lanes covering each 256B row (full-line, coalesced).
  if (iB != jB) {
    __syncthreads();  // all waves done with primary epilogue bufs
    ushort* Tm = smem;  // [128][128] ushort = 32KB, XOR-swz on 8B units
#pragma unroll
    for (int m = 0; m < 4; ++m)
#pragma unroll
      for (int n = 0; n < 4; ++n) {
        int cu = ((i0loc + m * 16) >> 2) + (lane >> 4);  // data col unit (0..31)
        int row = j0loc + n * 16 + (lane & 15);
        int u = cu ^ (row & 15);
        ushort4 val;
        val.x = f2bf(acc[m][n][0]);
        val.y = f2bf(acc[m][n][1]);
        val.z = f2bf(acc[m][n][2]);
        val.w = f2bf(acc[m][n][3]);
        *(ushort4*)&Tm[row * 128 + u * 4] = val;
      }
    __syncthreads();
    int colu = t & 31;  // 8B unit within row
    int rb = t >> 5;    // 8 rows per iteration
#pragma unroll
    for (int it = 0; it < 16; ++it) {
      int row = it * 8 + rb;
      int u = colu ^ (row & 15);
      *(ushort4*)(simb + (size_t)(jB + row) * 2048 + iB + colu * 4) =
          *(const ushort4*)&Tm[row * 128 + u * 4];
    }
  }
}

// ------- fused per-wave threshold select + finalize (bf16 sim) -----------
// Radix select counts ALL 16 elements via ballot (1 VALU each; bcnt/add on
// scalar pipe) — the old 8-local + 6-shfl path cost ~6 DS + 20 VALU per bit.
__global__ __launch_bounds__(256) void thrfin_kernel(float* __restrict__ A,
                                                     const float* __restrict__ imp,
                                                     const float* __restrict__ invSumP,
                                                     int bstart) {
  int brel = blockIdx.y;
  int b = bstart + brel;
  int wid = threadIdx.x >> 6;
  int lane = threadIdx.x & 63;
  int i = blockIdx.x * 4 + wid;
  ushort* row = (ushort*)A + ((size_t)brel * KN + i) * 2048;
  __shared__ float im[KN];
  ((float4*)im)[threadIdx.x] = ((const float4*)(imp + (size_t)b * KN))[threadIdx.x];
  __syncthreads();

  ushort4 v[4];
  unsigned key[16];
#pragma unroll
  for (int q = 0; q < 4; ++q) v[q] = ((const ushort4*)row)[lane + 64 * q];
#pragma unroll
  for (int q = 0; q < 4; ++q) {
    const ushort* pv = (const ushort*)&v[q];
#pragma unroll
    for (int e = 0; e < 4; ++e) {
      ushort u = pv[e];
      key[q * 4 + e] = (u & 0x8000u) ? (unsigned)(ushort)~u : (unsigned)(u | 0x8000u);
    }
  }
  unsigned tk = 0u;
#pragma unroll 1
  for (int bit = 15; bit >= 0; --bit) {
    unsigned cand = tk | (1u << bit);
    int c = 0;
#pragma unroll
    for (int e = 0; e < 16; ++e)
      c += (int)__popcll(__ballot(key[e] >= cand));
    if (c >= ADJ_KK) tk = cand;
  }
  float m[16];
  float s = 0.0f;
#pragma unroll
  for (int q = 0; q < 4; ++q) {
    const ushort* pv = (const ushort*)&v[q];
#pragma unroll
    for (int e = 0; e < 4; ++e) {
      float val = __uint_as_float(((unsigned)pv[e]) << 16);
      float mv = (key[q * 4 + e] >= tk) ? val : 0.0f;
      m[q * 4 + e] = mv;
      s += mv;
    }
  }
#pragma unroll
  for (int off = 32; off > 0; off >>= 1) s += __shfl_xor(s, off);
  float invF = 1.0f / (s + 1.0f + EPSF);
  float vi = im[i];
  float invP = invSumP[(size_t)b * KN + i];
#pragma unroll
  for (int q = 0; q < 4; ++q) {
    float4 iv = ((const float4*)im)[lane + 64 * q];
    const float* ip = (const float*)&iv;
    ushort4 r;
    ushort* rp = (ushort*)&r;
    int colb = 4 * lane + 256 * q;
#pragma unroll
    for (int e = 0; e < 4; ++e) {
      float diag = (colb + e == i) ? 1.0f : 0.0f;
      float d = vi - ip[e];
      rp[e] = f2bf((m[q * 4 + e] + diag) * invF + (__expf(-d * d * 0.125f) + diag) * invP);
    }
    ((ushort4*)row)[lane + 64 * q] = r;
  }
}

// ------- bf16 transpose INTO sim rows' back halves -----------------------
__global__ __launch_bounds__(256) void at_kernel(float* __restrict__ Asim) {
  int brel = blockIdx.z;
  int k0 = blockIdx.x * 64;
  int j0 = blockIdx.y * 64;
  __shared__ ushort t[64][68];
  ushort* Ab = (ushort*)(Asim + (size_t)brel * KN * KN);
  int g = threadIdx.x & 15;
  int r = threadIdx.x >> 4;
#pragma unroll
  for (int p = 0; p < 4; ++p) {
    int row = p * 16 + r;
    *(ushort4*)&t[row][g * 4] =
        *(const ushort4*)&Ab[(size_t)(k0 + row) * 2048 + j0 + g * 4];
  }
  __syncthreads();
#pragma unroll
  for (int p = 0; p < 4; ++p) {
    int j = p * 16 + r;
    ushort4 v;
    v.x = t[g * 4 + 0][j];
    v.y = t[g * 4 + 1][j];
    v.z = t[g * 4 + 2][j];
    v.w = t[g * 4 + 3][j];
    *(ushort4*)&Ab[(size_t)(j0 + j) * 2048 + 1024 + k0 + g * 4] = v;
  }
}

// ---------------- MFMA linear: hg[brel,o,k] = fac(k)*sum_c WT[o,c]*fT[k,c]
// fac = nrm[k] (layer 1) or mTK[k]*INV_DS*nrm[k] (layer 2).
// Epilogue aliased onto dead staging buffers.
template <int C, bool MASK>
__global__ __launch_bounds__(256) void linf_kernel(const ushort* __restrict__ xg,
                                                   const ushort* __restrict__ WT,
                                                   const float* __restrict__ nrm,
                                                   const float* __restrict__ mTK,
                                                   ushort* __restrict__ hg, int M,
                                                   int bstart) {
  int brel = blockIdx.z;
  int b = bstart + brel;
  int t = threadIdx.x;
  int lane = t & 63;
  int wid = t >> 6;
  int iB = blockIdx.y * 64;
  int jB = blockIdx.x * 128;
  const ushort* xb = xg + (size_t)brel * KN * C;

  __shared__ ushort smem[12288];  // Hs[2][2048] | Bs[2][4096]; ep aliases base
  ushort* HsB = smem;
  ushort* BsB = smem + 4096;

  int srow = t >> 2;
  int scol = (t & 3) * 8;
  int ldst = t * 8;

  auto stage = [&](int bufi, int c0) {
    gll16(WT + (size_t)(iB + srow) * C + c0 + scol, &HsB[bufi * 2048 + ldst]);
    gll16(xb + (size_t)(jB + srow) * C + c0 + scol, &BsB[bufi * 4096 + ldst]);
    gll16(xb + (size_t)(jB + 64 + srow) * C + c0 + scol, &BsB[bufi * 4096 + 2048 + ldst]);
  };

  int i0loc = (wid >> 1) * 32;
  int j0loc = (wid & 1) * 64;
  int r = lane & 15;
  int s = (lane >> 4) * 8;

  f32x4 acc[2][4] = {};
  stage(0, 0);
  __syncthreads();
  int cur = 0;
#pragma unroll 2
  for (int ks = 0; ks < C / 32; ++ks) {
    if (ks + 1 < C / 32) stage(cur ^ 1, (ks + 1) * 32);
    bf16x8 a[2], bb[4];
#pragma unroll
    for (int m = 0; m < 2; ++m)
      a[m] = *reinterpret_cast<const bf16x8*>(&HsB[cur * 2048 + (i0loc + m * 16 + r) * 32 + s]);
#pragma unroll
    for (int n = 0; n < 4; ++n)
      bb[n] = *reinterpret_cast<const bf16x8*>(&BsB[cur * 4096 + (j0loc + n * 16 + r) * 32 + s]);
#pragma unroll
    for (int m = 0; m < 2; ++m)
#pragma unroll
      for (int n = 0; n < 4; ++n)
        acc[m][n] = __builtin_amdgcn_mfma_f32_16x16x32_bf16(a[m], bb[n], acc[m][n], 0, 0, 0);
    __syncthreads();
    cur ^= 1;
  }

  float(*buf)[65] = (float(*)[65])((float*)smem + (size_t)wid * 16 * 65);
  int orow = (lane >> 4) * 4;
  int ocol = lane & 15;
  int i0 = iB + i0loc;
  int j0 = jB + j0loc;
#pragma unroll
  for (int m = 0; m < 2; ++m) {
#pragma unroll
    for (int n = 0; n < 4; ++n)
#pragma unroll
      for (int rr = 0; rr < 4; ++rr) buf[orow + rr][n * 16 + ocol] = acc[m][n][rr];
#pragma unroll
    for (int rr = 0; rr < 4; ++rr) {
      int row = rr * 4 + (lane >> 4);
      int kk = j0 + (lane & 15) * 4;
      float4 v4 = *(const float4*)&buf[row][(lane & 15) * 4];
      float4 nv = *(const float4*)(nrm + (size_t)b * KN + kk);
      float f0 = nv.x, f1 = nv.y, f2 = nv.z, f3 = nv.w;
      if (MASK) {
        float4 mv = *(const float4*)(mTK + (size_t)b * KN + kk);
        f0 *= mv.x * INV_DS;
        f1 *= mv.y * INV_DS;
        f2 *= mv.z * INV_DS;
        f3 *= mv.w * INV_DS;
      }
      ushort4 r4;
      r4.x = f2bf(v4.x * f0);
      r4.y = f2bf(v4.y * f1);
      r4.z = f2bf(v4.z * f2);
      r4.w = f2bf(v4.w * f3);
      *(ushort4*)(hg + ((size_t)brel * M + i0 + m * 16 + row) * KN + kk) = r4;
    }
  }
}

// ---------------- MFMA s = relu(h @ A), At read from sim back halves -----
// Epilogue aliased onto dead staging buffers (24KB LDS total).
template <int M, bool LOCAL>
__global__ __launch_bounds__(256) void sgemmf_kernel(const ushort* __restrict__ hB,
                                                     const float* __restrict__ Asim,
                                                     float* __restrict__ outp, int bstart) {
  int brel = blockIdx.z;
  int b = bstart + brel;
  int t = threadIdx.x;
  int lane = t & 63;
  int wid = t >> 6;
  int iB = blockIdx.y * 64;
  int jB = blockIdx.x * 128;
  const ushort* hb = hB + (size_t)(LOCAL ? brel : b) * M * KN;
  const ushort* Ab = (const ushort*)(Asim + (size_t)brel * KN * KN);

  __shared__ ushort smem[12288];  // Hs[2][2048] | Bs[2][4096]; ep aliases base
  ushort* HsB = smem;
  ushort* BsB = smem + 4096;

  int srow = t >> 2;
  int scol = (t & 3) * 8;
  int ldst = t * 8;

  auto stage = [&](int bufi, int k0) {
    gll16(hb + (size_t)(iB + srow) * KN + k0 + scol, &HsB[bufi * 2048 + ldst]);
    gll16(Ab + (size_t)(jB + srow) * 2048 + 1024 + k0 + scol, &BsB[bufi * 4096 + ldst]);
    gll16(Ab + (size_t)(jB + 64 + srow) * 2048 + 1024 + k0 + scol,
          &BsB[bufi * 4096 + 2048 + ldst]);
  };

  int i0loc = (wid >> 1) * 32;
  int j0loc = (wid & 1) * 64;
  int r = lane & 15;
  int s = (lane >> 4) * 8;

  f32x4 acc[2][4] = {};
  stage(0, 0);
  __syncthreads();
  int cur = 0;
#pragma unroll 2
  for (int ks = 0; ks < KN / 32; ++ks) {
    if (ks + 1 < KN / 32) stage(cur ^ 1, (ks + 1) * 32);
    bf16x8 a[2], bb[4];
#pragma unroll
    for (int m = 0; m < 2; ++m)
      a[m] = *reinterpret_cast<const bf16x8*>(&HsB[cur * 2048 + (i0loc + m * 16 + r) * 32 + s]);
#pragma unroll
    for (int n = 0; n < 4; ++n)
      bb[n] = *reinterpret_cast<const bf16x8*>(&BsB[cur * 4096 + (j0loc + n * 16 + r) * 32 + s]);
#pragma unroll
    for (int m = 0; m < 2; ++m)
#pragma unroll
      for (int n = 0; n < 4; ++n)
        acc[m][n] = __builtin_amdgcn_mfma_f32_16x16x32_bf16(a[m], bb[n], acc[m][n], 0, 0, 0);
    __syncthreads();
    cur ^= 1;
  }

  float(*buf)[65] = (float(*)[65])((float*)smem + (size_t)wid * 16 * 65);
  int orow = (lane >> 4) * 4;
  int ocol = lane & 15;
  int i0 = iB + i0loc;
  int j0 = jB + j0loc;
  float* ob = outp + (size_t)b * M * KN;
#pragma unroll
  for (int m = 0; m < 2; ++m) {
#pragma unroll
    for (int n = 0; n < 4; ++n)
#pragma unroll
      for (int rr = 0; rr < 4; ++rr) buf[orow + rr][n * 16 + ocol] = fmaxf(acc[m][n][rr], 0.0f);
#pragma unroll
    for (int rr = 0; rr < 4; ++rr) {
      int row = rr * 4 + (lane >> 4);
      float4 v4 = *(const float4*)&buf[row][(lane & 15) * 4];
      *(float4*)(ob + (size_t)(i0 + m * 16 + row) * KN + j0 + (lane & 15) * 4) = v4;
    }
  }
}

// ---------------- reductions ---------------------------------------------
__global__ void bag12_kernel(const float* __restrict__ emb1, const float* __restrict__ mTK,
                             const float* __restrict__ mTD, const float* __restrict__ imp,
                             float* __restrict__ bagk, float* __restrict__ bagd) {
  int c = blockIdx.x, b = blockIdx.y;
  int t = threadIdx.x;
  const float* e = emb1 + ((size_t)b * CMID + c) * KN;
  const float* ir = imp + (size_t)b * KN;
  const float* m1 = mTK + (size_t)b * KN;
  const float* m2 = mTD + (size_t)b * KN;
  float s1 = 0.0f, sd = 0.0f;
  for (int k = t; k < KN; k += 256) {
    float ev = e[k] * ir[k];
    s1 += ev * m1[k];
    sd += ev * m2[k];
  }
  __shared__ float r1[256], r2[256];
  r1[t] = s1;
  r2[t] = sd;
  __syncthreads();
  for (int st = 128; st > 0; st >>= 1) {
    if (t < st) {
      r1[t] += r1[t + st];
      r2[t] += r2[t + st];
    }
    __syncthreads();
  }
  if (t == 0) {
    bagk[(size_t)b * CMID + c] = r1[0] * INV_DS;
    bagd[(size_t)b * CMID + c] = r2[0] * INV_DS;
  }
}

__global__ void bag2_kernel(const float* __restrict__ s2, const float* __restrict__ mTK,
                            const float* __restrict__ imp, float* __restrict__ bag) {
  int o = blockIdx.x, b = blockIdx.y;
  int t = threadIdx.x;
  const float* sr = s2 + ((size_t)b * COUT + o) * KN;
  const float* ir = imp + (size_t)b * KN;
  const float* mr = mTK + (size_t)b * KN;
  float s = 0.0f;
  for (int k = t; k < KN; k += 256) s += sr[k] * mr[k] * ir[k];
  __shared__ float red[256];
  red[t] = s;
  __syncthreads();
  for (int st = 128; st > 0; st >>= 1) {
    if (t < st) red[t] += red[t + st];
    __syncthreads();
  }
  if (t == 0) bag[(size_t)b * COUT + o] = red[0];
}

__global__ void pooled_kernel(const float* __restrict__ x, const float* __restrict__ imp,
                              float* __restrict__ pooled) {
  int c = blockIdx.x, b = blockIdx.y;
  int t = threadIdx.x;
  const float* xr = x + (size_t)(b * CIN + c) * KN;
  const float* ir = imp + (size_t)b * KN;
  float s = 0.0f;
  for (int k = t; k < KN; k += 256) s += xr[k] * ir[k];
  __shared__ float red[256];
  red[t] = s;
  __syncthreads();
  for (int st = 128; st > 0; st >>= 1) {
    if (t < st) red[t] += red[t + st];
    __syncthreads();
  }
  if (t == 0) pooled[(size_t)b * CIN + c] = red[0];
}

__global__ void final_kernel(const float* __restrict__ pooled, const float* __restrict__ bag,
                             const float* __restrict__ id_w, const float* __restrict__ id_b,
                             const float* __restrict__ fc_w, float* __restrict__ out) {
  int b = blockIdx.x;
  int o = threadIdx.x;
  __shared__ float v[COUT];
  float s = id_b[o];
  const float* pr = pooled + (size_t)b * CIN;
  for (int c = 0; c < CIN; ++c) s += pr[c] * id_w[(size_t)c * COUT + o];
  v[o] = bag[(size_t)b * COUT + o] + fmaxf(s, 0.0f);
  __syncthreads();
  if (o < NCLS) {
    float acc = 0.0f;
    for (int oo = 0; oo < COUT; ++oo) acc += v[oo] * fc_w[(size_t)oo * NCLS + o];
    out[(size_t)b * NCLS + o] = acc;
  }
}

// ---------------- launch --------------------------------------------------
extern "C" void kernel_launch(void* const* d_in, const int* in_sizes, int n_in,
                              void* d_out, int out_size, void* d_ws, size_t ws_size,
                              hipStream_t stream) {
  const float* x = (const float*)d_in[0];
  const float* imp = (const float*)d_in[1];
  const float* rnd = (const float*)d_in[2];
  const float* W1 = (const float*)d_in[3];
  const float* W2 = (const float*)d_in[4];
  const float* fc_w = (const float*)d_in[5];
  const float* id_w = (const float*)d_in[6];
  const float* id_b = (const float*)d_in[7];
  float* out = (float*)d_out;
  float* emb1 = out + BN_ * NCLS;
  float* bagk = emb1 + (size_t)BN_ * CMID * KN;
  float* bagd = bagk + (size_t)BN_ * CMID;

  float* w = (float*)d_ws;
  size_t off = 0;
  auto take = [&](size_t n) {
    float* p = w + off;
    off += n;
    return p;
  };
  float* invSumP = take((size_t)BN_ * KN);
  float* invNX = take((size_t)BN_ * KN);
  float* invNE = take((size_t)BN_ * KN);
  float* nrmX = take((size_t)BN_ * KN);
  float* nrmE = take((size_t)BN_ * KN);
  float* topM = take((size_t)BN_ * KN);
  float* mTK = take((size_t)BN_ * KN);
  float* mTD = take((size_t)BN_ * KN);
  float* bag = take((size_t)BN_ * COUT);
  float* pooled = take((size_t)BN_ * CIN);
  ushort* W1T = (ushort*)take((size_t)CMID * CIN / 2);
  ushort* W2T = (ushort*)take((size_t)COUT * CMID / 2);

  const size_t s2_f = (size_t)BN_ * COUT * KN;
  const size_t xg1 = (size_t)CIN * KN / 2;    // per-batch xnT floats
  const size_t hg1 = (size_t)CMID * KN / 2;   // per-batch h floats
  const size_t eg1 = (size_t)CMID * KN / 2;   // per-batch enT floats
  const size_t hg2_1 = (size_t)COUT * KN / 2; // per-batch h2 floats

  size_t budget = ws_size / 4;
  int nb = 1;
  const int cands[6] = {32, 16, 8, 4, 2, 1};
  for (int ci = 0; ci < 6; ++ci) {
    size_t c = cands[ci];
    size_t uA = c * (xg1 + hg1);
    size_t uB = s2_f + c * (eg1 + hg2_1);
    size_t uMax = uA > uB ? uA : uB;
    if (off + uMax + c * (size_t)KN * KN <= budget) {
      nb = (int)c;
      break;
    }
  }
  size_t uA = (size_t)nb * (xg1 + hg1);
  size_t uB = s2_f + (size_t)nb * (eg1 + hg2_1);
  float* U = take(uA > uB ? uA : uB);
  ushort* xnT = (ushort*)U;
  ushort* h = (ushort*)(U + (size_t)nb * xg1);
  ushort* enT = (ushort*)U;
  ushort* h2 = (ushort*)(U + (size_t)nb * eg1);          // group-local
  float* s2 = U + (size_t)nb * (eg1 + hg2_1);
  float* simA = take((size_t)nb * KN * KN);

  maskpsum_kernel<<<dim3(KN / 64, BN_), 256, 0, stream>>>(imp, topM, invSumP);
  masks2_kernel<<<dim3(KN / 64, BN_), 256, 0, stream>>>(rnd, topM, mTK, mTD);
  colnorm_kernel<CIN><<<(BN_ * KN) / 256, 256, 0, stream>>>(x, invNX, nrmX);
  wtrans_kernel<CIN, CMID><<<(CMID * CIN) / 256, 256, 0, stream>>>(W1, W1T);
  wtrans_kernel<CMID, COUT><<<(COUT * CMID) / 256, 256, 0, stream>>>(W2, W2T);

  for (int bs = 0; bs < BN_; bs += nb) {
    xpose_kernel<CIN><<<dim3(KN / 64, CIN / 64, nb), 256, 0, stream>>>(
        x, invNX, (__hip_bfloat16*)xnT, bs);
    linf_kernel<CIN, false><<<dim3(KN / 128, CMID / 64, nb), 256, 0, stream>>>(
        xnT, W1T, nrmX, nullptr, h, CMID, bs);
    simf_kernel<CIN><<<nb * 36, 256, 0, stream>>>(xnT, simA, nb);
    thrfin_kernel<<<dim3(KN / 4, nb), 256, 0, stream>>>(simA, imp, invSumP, bs);
    at_kernel<<<dim3(KN / 64, KN / 64, nb), 256, 0, stream>>>(simA);
    sgemmf_kernel<CMID, true><<<dim3(KN / 128, CMID / 64, nb), 256, 0, stream>>>(h, simA, emb1,
                                                                                 bs);
  }

  colnorm_kernel<CMID><<<(BN_ * KN) / 256, 256, 0, stream>>>(emb1, invNE, nrmE);

  for (int bs = 0; bs < BN_; bs += nb) {
    xpose_kernel<CMID><<<dim3(KN / 64, CMID / 64, nb), 256, 0, stream>>>(
        emb1, invNE, (__hip_bfloat16*)enT, bs);
    linf_kernel<CMID, true><<<dim3(KN / 128, COUT / 64, nb), 256, 0, stream>>>(
        enT, W2T, nrmE, mTK, h2, COUT, bs);
    simf_kernel<CMID><<<nb * 36, 256, 0, stream>>>(enT, simA, nb);
    thrfin_kernel<<<dim3(KN / 4, nb), 256, 0, stream>>>(simA, imp, invSumP, bs);
    at_kernel<<<dim3(KN / 64, KN / 64, nb), 256, 0, stream>>>(simA);
    sgemmf_kernel<COUT, true><<<dim3(KN / 128, COUT / 64, nb), 256, 0, stream>>>(h2, simA, s2,
                                                                                 bs);
  }

  bag12_kernel<<<dim3(CMID, BN_), 256, 0, stream>>>(emb1, mTK, mTD, imp, bagk, bagd);
  bag2_kernel<<<dim3(COUT, BN_), 256, 0, stream>>>(s2, mTK, imp, bag);
  pooled_kernel<<<dim3(CIN, BN_), 256, 0, stream>>>(x, imp, pooled);
  final_kernel<<<BN_, 64, 0, stream>>>(pooled, bag, id_w, id_b, fc_w, out);
}